// Round 1
// baseline (4452.066 us; speedup 1.0000x reference)
//
#include <hip/hip_runtime.h>

// GCN: 3-layer GraphConv (norm='both') + mean over nodes.
// N=50000 nodes, E=800000 edges, all feature dims 128.
#define N_NODES 50000
#define N_EDGES 800000
#define F 128
#define SX_STRIDE 132  // 128 + 4 pad: breaks 4-way LDS bank conflict on sx[r][k], keeps 16B align

// ---- degree counting: deg_src (out) and deg_dst (in) via atomics ----
__global__ __launch_bounds__(256) void deg_kernel(const int* __restrict__ src,
                                                  const int* __restrict__ dst,
                                                  float* __restrict__ degs,
                                                  float* __restrict__ degd, int nE) {
    int e = blockIdx.x * 256 + threadIdx.x;
    if (e < nE) {
        atomicAdd(&degs[src[e]], 1.0f);
        atomicAdd(&degd[dst[e]], 1.0f);
    }
}

// ---- deg -> rsqrt(max(deg,1)) in place, over both norm arrays at once ----
__global__ __launch_bounds__(256) void norm_kernel(float* __restrict__ d, int n) {
    int i = blockIdx.x * 256 + threadIdx.x;
    if (i < n) d[i] = rsqrtf(fmaxf(d[i], 1.0f));
}

// ---- edge aggregation: m[dst] += x[src] * onorm[src]; 32 threads/edge, float4 ----
__global__ __launch_bounds__(256) void agg_kernel(const float* __restrict__ x,
                                                  float* __restrict__ m,
                                                  const int* __restrict__ src,
                                                  const int* __restrict__ dst,
                                                  const float* __restrict__ onorm, int nE) {
    unsigned t = blockIdx.x * 256u + threadIdx.x;
    unsigned e = t >> 5;           // edge id
    unsigned j = (t & 31u) * 4u;   // float offset within the 128-wide row
    if (e < (unsigned)nE) {
        int s = src[e], d = dst[e];
        float w = onorm[s];
        float4 v = *(const float4*)(x + (size_t)s * F + j);
        float* mp = m + (size_t)d * F + j;
        atomicAdd(mp + 0, v.x * w);
        atomicAdd(mp + 1, v.y * w);
        atomicAdd(mp + 2, v.z * w);
        atomicAdd(mp + 3, v.w * w);
    }
}

// ---- y[i,:] = act((m[i,:] * inorm[i]) @ W + b); 16 rows/block, 256 threads ----
// thread (r = tid>>4, c0 = (tid&15)*8) computes 8 consecutive output cols of one row.
// N_NODES = 3125 * 16 exactly, so no row-guard needed.
template <int RELU>
__global__ __launch_bounds__(256) void gemm_kernel(const float* __restrict__ m,
                                                   const float* __restrict__ inorm,
                                                   const float* __restrict__ W,
                                                   const float* __restrict__ b,
                                                   float* __restrict__ y, int nRows) {
    __shared__ float sx[16 * SX_STRIDE];
    int tid = threadIdx.x;
    int row0 = blockIdx.x * 16;

    // stage 16 input rows (scaled by inorm) into LDS
    const float4* mv = (const float4*)(m + (size_t)row0 * F);
    for (int i = tid; i < 16 * F / 4; i += 256) {
        int r = i >> 5;
        int col4 = (i & 31) * 4;
        float4 v = mv[i];
        float w = inorm[row0 + r];
        v.x *= w; v.y *= w; v.z *= w; v.w *= w;
        *(float4*)(sx + r * SX_STRIDE + col4) = v;
    }
    __syncthreads();

    int r = tid >> 4;
    int c0 = (tid & 15) * 8;
    float acc[8];
#pragma unroll
    for (int q = 0; q < 8; q++) acc[q] = b[c0 + q];

    const float* xr = sx + r * SX_STRIDE;
    for (int k = 0; k < F; k++) {
        float xv = xr[k];
        const float4* wv = (const float4*)(W + k * F + c0);
        float4 w0 = wv[0], w1 = wv[1];
        acc[0] += xv * w0.x; acc[1] += xv * w0.y;
        acc[2] += xv * w0.z; acc[3] += xv * w0.w;
        acc[4] += xv * w1.x; acc[5] += xv * w1.y;
        acc[6] += xv * w1.z; acc[7] += xv * w1.w;
    }

    float* yp = y + (size_t)(row0 + r) * F + c0;
#pragma unroll
    for (int q = 0; q < 8; q++) {
        float v = acc[q];
        if (RELU) v = fmaxf(v, 0.0f);
        yp[q] = v;
    }
}

// ---- c[j] = (1/N) * sum_i m[i,j] * inorm[i]  (column mean of scaled agg) ----
__global__ __launch_bounds__(128) void colmean_kernel(const float* __restrict__ m,
                                                      const float* __restrict__ inorm,
                                                      float* __restrict__ c, int nRows) {
    int col = threadIdx.x;
    float acc = 0.0f;
    for (int i = blockIdx.x; i < nRows; i += gridDim.x)
        acc += m[(size_t)i * F + col] * inorm[i];
    atomicAdd(&c[col], acc * (1.0f / (float)N_NODES));
}

// ---- out[j] = b3[j] + sum_k c[k] * W3[k,j]  (tiny matvec, one block) ----
__global__ __launch_bounds__(128) void out_kernel(const float* __restrict__ c,
                                                  const float* __restrict__ W,
                                                  const float* __restrict__ b,
                                                  float* __restrict__ out) {
    int j = threadIdx.x;
    float acc = b[j];
    for (int k = 0; k < F; k++) acc += c[k] * W[k * F + j];
    out[j] = acc;
}

extern "C" void kernel_launch(void* const* d_in, const int* in_sizes, int n_in,
                              void* d_out, int out_size, void* d_ws, size_t ws_size,
                              hipStream_t stream) {
    const float* feat = (const float*)d_in[0];
    const float* W1   = (const float*)d_in[1];
    const float* b1   = (const float*)d_in[2];
    const float* W2   = (const float*)d_in[3];
    const float* b2   = (const float*)d_in[4];
    const float* W3   = (const float*)d_in[5];
    const float* b3   = (const float*)d_in[6];
    const int*   src  = (const int*)d_in[7];
    const int*   dst  = (const int*)d_in[8];
    float* out = (float*)d_out;

    // workspace layout (all 16B-aligned offsets)
    char* ws = (char*)d_ws;
    float* m     = (float*)ws;                                   // N*F floats
    float* h     = (float*)(ws + (size_t)N_NODES * F * 4);       // N*F floats
    float* onorm = (float*)(ws + (size_t)2 * N_NODES * F * 4);   // N floats
    float* inorm = onorm + N_NODES;                              // N floats
    float* c     = inorm + N_NODES;                              // F floats

    const int AGG_BLOCKS = (N_EDGES * 32) / 256;  // 100000 exactly
    const int GEMM_BLOCKS = N_NODES / 16;         // 3125 exactly

    // norms (also zero c here; it's only written at the very end)
    hipMemsetAsync(onorm, 0, (2 * N_NODES + F) * sizeof(float), stream);
    deg_kernel<<<(N_EDGES + 255) / 256, 256, 0, stream>>>(src, dst, onorm, inorm, N_EDGES);
    norm_kernel<<<(2 * N_NODES + 255) / 256, 256, 0, stream>>>(onorm, 2 * N_NODES);

    // layer 1: agg(feat) -> m, gemm+relu -> h
    hipMemsetAsync(m, 0, (size_t)N_NODES * F * 4, stream);
    agg_kernel<<<AGG_BLOCKS, 256, 0, stream>>>(feat, m, src, dst, onorm, N_EDGES);
    gemm_kernel<1><<<GEMM_BLOCKS, 256, 0, stream>>>(m, inorm, W1, b1, h, N_NODES);

    // layer 2: agg(h) -> m, gemm+relu -> h (overwrite ok: m holds the data)
    hipMemsetAsync(m, 0, (size_t)N_NODES * F * 4, stream);
    agg_kernel<<<AGG_BLOCKS, 256, 0, stream>>>(h, m, src, dst, onorm, N_EDGES);
    gemm_kernel<1><<<GEMM_BLOCKS, 256, 0, stream>>>(m, inorm, W2, b2, h, N_NODES);

    // layer 3: agg(h) -> m, then mean-fusion: out = (mean_i m[i]*inorm[i]) @ W3 + b3
    hipMemsetAsync(m, 0, (size_t)N_NODES * F * 4, stream);
    agg_kernel<<<AGG_BLOCKS, 256, 0, stream>>>(h, m, src, dst, onorm, N_EDGES);
    colmean_kernel<<<512, 128, 0, stream>>>(m, inorm, c, N_NODES);
    out_kernel<<<1, 128, 0, stream>>>(c, W3, b3, out);
}

// Round 2
// 743.228 us; speedup vs baseline: 5.9902x; 5.9902x over previous
//
#include <hip/hip_runtime.h>

// GCN: 3-layer GraphConv (norm='both') + mean over nodes.
// Round 2: atomic-free aggregation via device-built CSR (dst-sorted edges).
#define N_NODES 50000
#define N_EDGES 800000
#define F 128
#define SX_STRIDE 132  // 128 + 4 pad: breaks LDS bank conflict on sx[r][k]

// ---- degree counting (int atomics on 200 KB tables — L2-resident, cheap) ----
__global__ __launch_bounds__(256) void deg_kernel(const int* __restrict__ src,
                                                  const int* __restrict__ dst,
                                                  int* __restrict__ degs,
                                                  int* __restrict__ degd, int nE) {
    int e = blockIdx.x * 256 + threadIdx.x;
    if (e < nE) {
        atomicAdd(&degs[src[e]], 1);
        atomicAdd(&degd[dst[e]], 1);
    }
}

// ---- norms: onorm = rsqrt(max(deg_src,1)), inorm = rsqrt(max(deg_dst,1)) ----
__global__ __launch_bounds__(256) void norm_kernel(const int* __restrict__ degs,
                                                   const int* __restrict__ degd,
                                                   float* __restrict__ onorm,
                                                   float* __restrict__ inorm, int n) {
    int i = blockIdx.x * 256 + threadIdx.x;
    if (i < n) {
        onorm[i] = rsqrtf(fmaxf((float)degs[i], 1.0f));
        inorm[i] = rsqrtf(fmaxf((float)degd[i], 1.0f));
    }
}

// ---- exclusive scan of deg_dst -> row_ptr (and cursor copy); single block ----
__global__ __launch_bounds__(1024) void scan_kernel(const int* __restrict__ deg,
                                                    int* __restrict__ row_ptr,
                                                    int* __restrict__ cursor) {
    __shared__ int part[1024];
    const int CH = (N_NODES + 1023) / 1024;  // 49
    int t = threadIdx.x;
    int s0 = t * CH, e0 = min(s0 + CH, N_NODES);
    int sum = 0;
    for (int i = s0; i < e0; i++) sum += deg[i];
    part[t] = sum;
    __syncthreads();
    // Hillis-Steele inclusive scan over 1024 partials
    for (int off = 1; off < 1024; off <<= 1) {
        int v = (t >= off) ? part[t - off] : 0;
        __syncthreads();
        part[t] += v;
        __syncthreads();
    }
    int base = part[t] - sum;  // exclusive prefix
    for (int i = s0; i < e0; i++) {
        row_ptr[i] = base; cursor[i] = base; base += deg[i];
    }
    if (s0 < N_NODES && e0 == N_NODES) row_ptr[N_NODES] = base;  // == E
}

// ---- scatter edges into dst-sorted order; also pre-gather onorm[src] ----
__global__ __launch_bounds__(256) void scatter_kernel(const int* __restrict__ src,
                                                      const int* __restrict__ dst,
                                                      const float* __restrict__ onorm,
                                                      int* __restrict__ cursor,
                                                      int* __restrict__ esrc,
                                                      float* __restrict__ wsrc, int nE) {
    int e = blockIdx.x * 256 + threadIdx.x;
    if (e < nE) {
        int s = src[e];
        int pos = atomicAdd(&cursor[dst[e]], 1);
        esrc[pos] = s;
        wsrc[pos] = onorm[s];
    }
}

// ---- atomic-free aggregation: one wave per dst row ----
// m[i,:] = inorm[i] * sum_{e in CSR[i]} x[esrc[e],:] * wsrc[e]
// lane j holds floats [2j, 2j+1] of the 128-wide row; unroll-by-2 over edges.
__global__ __launch_bounds__(256) void agg_csr_kernel(const float* __restrict__ x,
                                                      float* __restrict__ m,
                                                      const int* __restrict__ row_ptr,
                                                      const int* __restrict__ esrc,
                                                      const float* __restrict__ wsrc,
                                                      const float* __restrict__ inorm) {
    int row = blockIdx.x * 4 + (threadIdx.x >> 6);   // 4 waves/block, 1 row/wave
    int lane = threadIdx.x & 63;
    int beg = row_ptr[row], end = row_ptr[row + 1];
    const float* xl = x + lane * 2;
    float ax = 0.0f, ay = 0.0f;
    int e = beg;
    for (; e + 1 < end; e += 2) {
        int s0 = esrc[e], s1 = esrc[e + 1];
        float w0 = wsrc[e], w1 = wsrc[e + 1];
        float2 v0 = *(const float2*)(xl + (size_t)s0 * F);
        float2 v1 = *(const float2*)(xl + (size_t)s1 * F);
        ax += v0.x * w0 + v1.x * w1;
        ay += v0.y * w0 + v1.y * w1;
    }
    if (e < end) {
        int s = esrc[e]; float w = wsrc[e];
        float2 v = *(const float2*)(xl + (size_t)s * F);
        ax += v.x * w; ay += v.y * w;
    }
    float inw = inorm[row];
    float2 o; o.x = ax * inw; o.y = ay * inw;
    *(float2*)(m + (size_t)row * F + lane * 2) = o;
}

// ---- y[i,:] = act(m[i,:] @ W + b); 16 rows/block, 256 threads ----
template <int RELU>
__global__ __launch_bounds__(256) void gemm_kernel(const float* __restrict__ m,
                                                   const float* __restrict__ W,
                                                   const float* __restrict__ b,
                                                   float* __restrict__ y, int nRows) {
    __shared__ float sx[16 * SX_STRIDE];
    int tid = threadIdx.x;
    int row0 = blockIdx.x * 16;

    const float4* mv = (const float4*)(m + (size_t)row0 * F);
    for (int i = tid; i < 16 * F / 4; i += 256) {
        int r = i >> 5;
        int col4 = (i & 31) * 4;
        *(float4*)(sx + r * SX_STRIDE + col4) = mv[i];
    }
    __syncthreads();

    int r = tid >> 4;
    int c0 = (tid & 15) * 8;
    float acc[8];
#pragma unroll
    for (int q = 0; q < 8; q++) acc[q] = b[c0 + q];

    const float* xr = sx + r * SX_STRIDE;
    for (int k = 0; k < F; k++) {
        float xv = xr[k];
        const float4* wv = (const float4*)(W + k * F + c0);
        float4 w0 = wv[0], w1 = wv[1];
        acc[0] += xv * w0.x; acc[1] += xv * w0.y;
        acc[2] += xv * w0.z; acc[3] += xv * w0.w;
        acc[4] += xv * w1.x; acc[5] += xv * w1.y;
        acc[6] += xv * w1.z; acc[7] += xv * w1.w;
    }

    float* yp = y + (size_t)(row0 + r) * F + c0;
#pragma unroll
    for (int q = 0; q < 8; q++) {
        float v = acc[q];
        if (RELU) v = fmaxf(v, 0.0f);
        yp[q] = v;
    }
}

// ---- c[j] = (1/N) * sum_i m[i,j]  (inorm already folded into m) ----
__global__ __launch_bounds__(128) void colmean_kernel(const float* __restrict__ m,
                                                      float* __restrict__ c, int nRows) {
    int col = threadIdx.x;
    float acc = 0.0f;
    for (int i = blockIdx.x; i < nRows; i += gridDim.x)
        acc += m[(size_t)i * F + col];
    atomicAdd(&c[col], acc * (1.0f / (float)N_NODES));
}

// ---- out[j] = b3[j] + sum_k c[k] * W3[k,j] ----
__global__ __launch_bounds__(128) void out_kernel(const float* __restrict__ c,
                                                  const float* __restrict__ W,
                                                  const float* __restrict__ b,
                                                  float* __restrict__ out) {
    int j = threadIdx.x;
    float acc = b[j];
    for (int k = 0; k < F; k++) acc += c[k] * W[k * F + j];
    out[j] = acc;
}

extern "C" void kernel_launch(void* const* d_in, const int* in_sizes, int n_in,
                              void* d_out, int out_size, void* d_ws, size_t ws_size,
                              hipStream_t stream) {
    const float* feat = (const float*)d_in[0];
    const float* W1   = (const float*)d_in[1];
    const float* b1   = (const float*)d_in[2];
    const float* W2   = (const float*)d_in[3];
    const float* b2   = (const float*)d_in[4];
    const float* W3   = (const float*)d_in[5];
    const float* b3   = (const float*)d_in[6];
    const int*   src  = (const int*)d_in[7];
    const int*   dst  = (const int*)d_in[8];
    float* out = (float*)d_out;

    // workspace layout
    char* ws = (char*)d_ws;
    size_t off = 0;
    float* m       = (float*)(ws + off); off += (size_t)N_NODES * F * 4;
    float* h       = (float*)(ws + off); off += (size_t)N_NODES * F * 4;
    float* onorm   = (float*)(ws + off); off += N_NODES * 4;
    float* inorm   = (float*)(ws + off); off += N_NODES * 4;
    int*   row_ptr = (int*)  (ws + off); off += (N_NODES + 1) * 4;
    int*   cursor  = (int*)  (ws + off); off += N_NODES * 4;
    // deg_src, deg_dst, c contiguous -> single memset
    int*   deg_src = (int*)  (ws + off); off += N_NODES * 4;
    int*   deg_dst = (int*)  (ws + off); off += N_NODES * 4;
    float* c       = (float*)(ws + off); off += F * 4;
    int*   esrc    = (int*)  (ws + off); off += (size_t)N_EDGES * 4;
    float* wsrc    = (float*)(ws + off); off += (size_t)N_EDGES * 4;

    const int EB = (N_EDGES + 255) / 256;     // 3125
    const int AGG_BLOCKS = N_NODES / 4;       // 12500 (4 waves/block, 1 row/wave)
    const int GEMM_BLOCKS = N_NODES / 16;     // 3125

    // zero only what accumulates: deg_src|deg_dst|c (contiguous)
    hipMemsetAsync(deg_src, 0, (2 * N_NODES + F) * sizeof(int), stream);

    // CSR build
    deg_kernel<<<EB, 256, 0, stream>>>(src, dst, deg_src, deg_dst, N_EDGES);
    norm_kernel<<<(N_NODES + 255) / 256, 256, 0, stream>>>(deg_src, deg_dst, onorm, inorm, N_NODES);
    scan_kernel<<<1, 1024, 0, stream>>>(deg_dst, row_ptr, cursor);
    scatter_kernel<<<EB, 256, 0, stream>>>(src, dst, onorm, cursor, esrc, wsrc, N_EDGES);

    // layer 1
    agg_csr_kernel<<<AGG_BLOCKS, 256, 0, stream>>>(feat, m, row_ptr, esrc, wsrc, inorm);
    gemm_kernel<1><<<GEMM_BLOCKS, 256, 0, stream>>>(m, W1, b1, h, N_NODES);
    // layer 2
    agg_csr_kernel<<<AGG_BLOCKS, 256, 0, stream>>>(h, m, row_ptr, esrc, wsrc, inorm);
    gemm_kernel<1><<<GEMM_BLOCKS, 256, 0, stream>>>(m, W2, b2, h, N_NODES);
    // layer 3 + mean fusion: out = (mean_i m[i,:]) @ W3 + b3
    agg_csr_kernel<<<AGG_BLOCKS, 256, 0, stream>>>(h, m, row_ptr, esrc, wsrc, inorm);
    colmean_kernel<<<512, 128, 0, stream>>>(m, c, N_NODES);
    out_kernel<<<1, 128, 0, stream>>>(c, W3, b3, out);
}

// Round 3
// 607.025 us; speedup vs baseline: 7.3342x; 1.2244x over previous
//
#include <hip/hip_runtime.h>

// GCN: 3-layer GraphConv (norm='both') + mean over nodes.
// Round 3: hierarchical scan (kill 110us single-block scan) + packed-edge
// uniform-row aggregation (one 64-thread wave per dst row).
#define N_NODES 50000
#define N_EDGES 800000
#define F 128
#define SX_STRIDE 132   // 128 + 4 pad: breaks LDS bank conflict on sx[r][k]
#define SCAN_NB 49      // ceil(50000/1024)

// ---- degree counting (int atomics on 200 KB tables — L2-resident) ----
__global__ __launch_bounds__(256) void deg_kernel(const int* __restrict__ src,
                                                  const int* __restrict__ dst,
                                                  int* __restrict__ degs,
                                                  int* __restrict__ degd, int nE) {
    int e = blockIdx.x * 256 + threadIdx.x;
    if (e < nE) {
        atomicAdd(&degs[src[e]], 1);
        atomicAdd(&degd[dst[e]], 1);
    }
}

// ---- norms: onorm = rsqrt(max(deg_src,1)), inorm = rsqrt(max(deg_dst,1)) ----
__global__ __launch_bounds__(256) void norm_kernel(const int* __restrict__ degs,
                                                   const int* __restrict__ degd,
                                                   float* __restrict__ onorm,
                                                   float* __restrict__ inorm, int n) {
    int i = blockIdx.x * 256 + threadIdx.x;
    if (i < n) {
        onorm[i] = rsqrtf(fmaxf((float)degs[i], 1.0f));
        inorm[i] = rsqrtf(fmaxf((float)degd[i], 1.0f));
    }
}

// ---- scan phase A: per-block (1024 elems) sums ----
__global__ __launch_bounds__(1024) void scanA_kernel(const int* __restrict__ deg,
                                                     int* __restrict__ blockSums) {
    __shared__ int wsum[16];
    int i = blockIdx.x * 1024 + threadIdx.x;
    int v = (i < N_NODES) ? deg[i] : 0;
#pragma unroll
    for (int off = 32; off; off >>= 1) v += __shfl_down(v, off);
    if ((threadIdx.x & 63) == 0) wsum[threadIdx.x >> 6] = v;
    __syncthreads();
    if (threadIdx.x == 0) {
        int s = 0;
#pragma unroll
        for (int k = 0; k < 16; k++) s += wsum[k];
        blockSums[blockIdx.x] = s;
    }
}

// ---- scan phase B: exclusive scan of SCAN_NB block sums (one wave) ----
__global__ __launch_bounds__(64) void scanB_kernel(const int* __restrict__ blockSums,
                                                   int* __restrict__ blockOffs) {
    int t = threadIdx.x;
    int v = (t < SCAN_NB) ? blockSums[t] : 0;
    int incl = v;
#pragma unroll
    for (int off = 1; off < 64; off <<= 1) {
        int u = __shfl_up(incl, off);
        if (t >= off) incl += u;
    }
    if (t < SCAN_NB) blockOffs[t] = incl - v;
}

// ---- scan phase C: intra-block scan + block offset -> cursor (== row_ptr) ----
// cursor[i] = exclusive prefix of deg_dst. After scatter bumps it by deg,
// cursor[i] == row_ptr[i+1]; agg uses cursor[row-1]..cursor[row].
__global__ __launch_bounds__(1024) void scanC_kernel(const int* __restrict__ deg,
                                                     const int* __restrict__ blockOffs,
                                                     int* __restrict__ cursor) {
    __shared__ int wsum[16];
    int t = threadIdx.x, lane = t & 63, w = t >> 6;
    int i = blockIdx.x * 1024 + t;
    int v = (i < N_NODES) ? deg[i] : 0;
    int incl = v;
#pragma unroll
    for (int off = 1; off < 64; off <<= 1) {
        int u = __shfl_up(incl, off);
        if (lane >= off) incl += u;
    }
    if (lane == 63) wsum[w] = incl;
    __syncthreads();
    if (t == 0) {
        int s = 0;
#pragma unroll
        for (int k = 0; k < 16; k++) { int x = wsum[k]; wsum[k] = s; s += x; }
    }
    __syncthreads();
    incl += wsum[w] + blockOffs[blockIdx.x];
    if (i < N_NODES) cursor[i] = incl - v;   // exclusive prefix
}

// ---- scatter edges into dst-sorted order, packed (src, onorm[src]) ----
__global__ __launch_bounds__(256) void scatter_kernel(const int* __restrict__ src,
                                                      const int* __restrict__ dst,
                                                      const float* __restrict__ onorm,
                                                      int* __restrict__ cursor,
                                                      int2* __restrict__ epack, int nE) {
    int e = blockIdx.x * 256 + threadIdx.x;
    if (e < nE) {
        int s = src[e];
        int pos = atomicAdd(&cursor[dst[e]], 1);
        int2 p; p.x = s; p.y = __float_as_int(onorm[s]);
        epack[pos] = p;
    }
}

// ---- atomic-free aggregation: one 64-thread wave per dst row ----
// row = blockIdx.x is wave-uniform -> edge-list reads can go scalar.
// m[row,:] = inorm[row] * sum_e x[epack[e].x,:] * w(epack[e])
__global__ __launch_bounds__(64) void agg_csr_kernel(const float* __restrict__ x,
                                                     float* __restrict__ m,
                                                     const int* __restrict__ cursor,
                                                     const int2* __restrict__ epack,
                                                     const float* __restrict__ inorm) {
    int row = blockIdx.x;
    int lane = threadIdx.x;
    int beg = (row == 0) ? 0 : cursor[row - 1];
    int end = cursor[row];
    const float* xl = x + lane * 2;
    float ax = 0.0f, ay = 0.0f;
    int e = beg;
    for (; e + 3 < end; e += 4) {
        int2 p0 = epack[e],     p1 = epack[e + 1];
        int2 p2 = epack[e + 2], p3 = epack[e + 3];
        float2 v0 = *(const float2*)(xl + (size_t)p0.x * F);
        float2 v1 = *(const float2*)(xl + (size_t)p1.x * F);
        float2 v2 = *(const float2*)(xl + (size_t)p2.x * F);
        float2 v3 = *(const float2*)(xl + (size_t)p3.x * F);
        float w0 = __int_as_float(p0.y), w1 = __int_as_float(p1.y);
        float w2 = __int_as_float(p2.y), w3 = __int_as_float(p3.y);
        ax += v0.x * w0 + v1.x * w1 + v2.x * w2 + v3.x * w3;
        ay += v0.y * w0 + v1.y * w1 + v2.y * w2 + v3.y * w3;
    }
    for (; e < end; e++) {
        int2 p = epack[e];
        float2 v = *(const float2*)(xl + (size_t)p.x * F);
        float w = __int_as_float(p.y);
        ax += v.x * w; ay += v.y * w;
    }
    float inw = inorm[row];
    float2 o; o.x = ax * inw; o.y = ay * inw;
    *(float2*)(m + (size_t)row * F + lane * 2) = o;
}

// ---- y[i,:] = act(m[i,:] @ W + b); 16 rows/block, 256 threads ----
template <int RELU>
__global__ __launch_bounds__(256) void gemm_kernel(const float* __restrict__ m,
                                                   const float* __restrict__ W,
                                                   const float* __restrict__ b,
                                                   float* __restrict__ y, int nRows) {
    __shared__ float sx[16 * SX_STRIDE];
    int tid = threadIdx.x;
    int row0 = blockIdx.x * 16;

    const float4* mv = (const float4*)(m + (size_t)row0 * F);
    for (int i = tid; i < 16 * F / 4; i += 256) {
        int r = i >> 5;
        int col4 = (i & 31) * 4;
        *(float4*)(sx + r * SX_STRIDE + col4) = mv[i];
    }
    __syncthreads();

    int r = tid >> 4;
    int c0 = (tid & 15) * 8;
    float acc[8];
#pragma unroll
    for (int q = 0; q < 8; q++) acc[q] = b[c0 + q];

    const float* xr = sx + r * SX_STRIDE;
    for (int k = 0; k < F; k++) {
        float xv = xr[k];
        const float4* wv = (const float4*)(W + k * F + c0);
        float4 w0 = wv[0], w1 = wv[1];
        acc[0] += xv * w0.x; acc[1] += xv * w0.y;
        acc[2] += xv * w0.z; acc[3] += xv * w0.w;
        acc[4] += xv * w1.x; acc[5] += xv * w1.y;
        acc[6] += xv * w1.z; acc[7] += xv * w1.w;
    }

    float* yp = y + (size_t)(row0 + r) * F + c0;
#pragma unroll
    for (int q = 0; q < 8; q++) {
        float v = acc[q];
        if (RELU) v = fmaxf(v, 0.0f);
        yp[q] = v;
    }
}

// ---- c[j] = (1/N) * sum_i m[i,j]  (inorm already folded into m) ----
__global__ __launch_bounds__(128) void colmean_kernel(const float* __restrict__ m,
                                                      float* __restrict__ c, int nRows) {
    int col = threadIdx.x;
    float acc = 0.0f;
    for (int i = blockIdx.x; i < nRows; i += gridDim.x)
        acc += m[(size_t)i * F + col];
    atomicAdd(&c[col], acc * (1.0f / (float)N_NODES));
}

// ---- out[j] = b3[j] + sum_k c[k] * W3[k,j] ----
__global__ __launch_bounds__(128) void out_kernel(const float* __restrict__ c,
                                                  const float* __restrict__ W,
                                                  const float* __restrict__ b,
                                                  float* __restrict__ out) {
    int j = threadIdx.x;
    float acc = b[j];
    for (int k = 0; k < F; k++) acc += c[k] * W[k * F + j];
    out[j] = acc;
}

extern "C" void kernel_launch(void* const* d_in, const int* in_sizes, int n_in,
                              void* d_out, int out_size, void* d_ws, size_t ws_size,
                              hipStream_t stream) {
    const float* feat = (const float*)d_in[0];
    const float* W1   = (const float*)d_in[1];
    const float* b1   = (const float*)d_in[2];
    const float* W2   = (const float*)d_in[3];
    const float* b2   = (const float*)d_in[4];
    const float* W3   = (const float*)d_in[5];
    const float* b3   = (const float*)d_in[6];
    const int*   src  = (const int*)d_in[7];
    const int*   dst  = (const int*)d_in[8];
    float* out = (float*)d_out;

    // workspace layout (word offsets; all arrays 4B types, epack 8B-aligned)
    char* ws = (char*)d_ws;
    size_t off = 0;
    float* m       = (float*)(ws + off); off += (size_t)N_NODES * F * 4;
    float* h       = (float*)(ws + off); off += (size_t)N_NODES * F * 4;
    float* onorm   = (float*)(ws + off); off += N_NODES * 4;
    float* inorm   = (float*)(ws + off); off += N_NODES * 4;
    int*   cursor  = (int*)  (ws + off); off += N_NODES * 4;
    int*   bsums   = (int*)  (ws + off); off += 64 * 4;
    int*   boffs   = (int*)  (ws + off); off += 64 * 4;
    // deg_src|deg_dst|c contiguous -> single memset
    int*   deg_src = (int*)  (ws + off); off += N_NODES * 4;
    int*   deg_dst = (int*)  (ws + off); off += N_NODES * 4;
    float* c       = (float*)(ws + off); off += F * 4;
    int2*  epack   = (int2*) (ws + off); off += (size_t)N_EDGES * 8;

    const int EB = (N_EDGES + 255) / 256;     // 3125
    const int GEMM_BLOCKS = N_NODES / 16;     // 3125

    // zero only what accumulates: deg_src|deg_dst|c (contiguous)
    hipMemsetAsync(deg_src, 0, (2 * N_NODES + F) * sizeof(int), stream);

    // CSR build
    deg_kernel<<<EB, 256, 0, stream>>>(src, dst, deg_src, deg_dst, N_EDGES);
    norm_kernel<<<(N_NODES + 255) / 256, 256, 0, stream>>>(deg_src, deg_dst, onorm, inorm, N_NODES);
    scanA_kernel<<<SCAN_NB, 1024, 0, stream>>>(deg_dst, bsums);
    scanB_kernel<<<1, 64, 0, stream>>>(bsums, boffs);
    scanC_kernel<<<SCAN_NB, 1024, 0, stream>>>(deg_dst, boffs, cursor);
    scatter_kernel<<<EB, 256, 0, stream>>>(src, dst, onorm, cursor, epack, N_EDGES);

    // layer 1
    agg_csr_kernel<<<N_NODES, 64, 0, stream>>>(feat, m, cursor, epack, inorm);
    gemm_kernel<1><<<GEMM_BLOCKS, 256, 0, stream>>>(m, W1, b1, h, N_NODES);
    // layer 2
    agg_csr_kernel<<<N_NODES, 64, 0, stream>>>(h, m, cursor, epack, inorm);
    gemm_kernel<1><<<GEMM_BLOCKS, 256, 0, stream>>>(m, W2, b2, h, N_NODES);
    // layer 3 + mean fusion: out = (mean_i m[i,:]) @ W3 + b3
    agg_csr_kernel<<<N_NODES, 64, 0, stream>>>(h, m, cursor, epack, inorm);
    colmean_kernel<<<512, 128, 0, stream>>>(m, c, N_NODES);
    out_kernel<<<1, 128, 0, stream>>>(c, W3, b3, out);
}

// Round 4
// 413.469 us; speedup vs baseline: 10.7676x; 1.4681x over previous
//
#include <hip/hip_runtime.h>

// GCN: 3-layer GraphConv (norm='both') + mean over nodes.
// Round 4: bf16 MFMA GEMM (W split hi+lo for fp32-grade weight precision),
// bf16 activations halve aggregation gather bytes.
#define N_NODES 50000
#define N_EDGES 800000
#define F 128
#define SCAN_NB 49      // ceil(50000/1024)

typedef __bf16 bf16x8 __attribute__((ext_vector_type(8)));
typedef float  f32x4  __attribute__((ext_vector_type(4)));

__device__ inline unsigned short f2bf(float f) {  // RNE fp32 -> bf16 bits
    unsigned u = __float_as_uint(f);
    u += 0x7FFF + ((u >> 16) & 1);
    return (unsigned short)(u >> 16);
}
__device__ inline float bflo2f(unsigned u) { return __uint_as_float(u << 16); }
__device__ inline float bfhi2f(unsigned u) { return __uint_as_float(u & 0xFFFF0000u); }

// ---- degree counting (int atomics on 200 KB tables — L2-resident) ----
__global__ __launch_bounds__(256) void deg_kernel(const int* __restrict__ src,
                                                  const int* __restrict__ dst,
                                                  int* __restrict__ degs,
                                                  int* __restrict__ degd, int nE) {
    int e = blockIdx.x * 256 + threadIdx.x;
    if (e < nE) {
        atomicAdd(&degs[src[e]], 1);
        atomicAdd(&degd[dst[e]], 1);
    }
}

// ---- norms ----
__global__ __launch_bounds__(256) void norm_kernel(const int* __restrict__ degs,
                                                   const int* __restrict__ degd,
                                                   float* __restrict__ onorm,
                                                   float* __restrict__ inorm, int n) {
    int i = blockIdx.x * 256 + threadIdx.x;
    if (i < n) {
        onorm[i] = rsqrtf(fmaxf((float)degs[i], 1.0f));
        inorm[i] = rsqrtf(fmaxf((float)degd[i], 1.0f));
    }
}

// ---- hierarchical scan: A (block sums), B (scan 49 sums), C (apply) ----
__global__ __launch_bounds__(1024) void scanA_kernel(const int* __restrict__ deg,
                                                     int* __restrict__ blockSums) {
    __shared__ int wsum[16];
    int i = blockIdx.x * 1024 + threadIdx.x;
    int v = (i < N_NODES) ? deg[i] : 0;
#pragma unroll
    for (int off = 32; off; off >>= 1) v += __shfl_down(v, off);
    if ((threadIdx.x & 63) == 0) wsum[threadIdx.x >> 6] = v;
    __syncthreads();
    if (threadIdx.x == 0) {
        int s = 0;
#pragma unroll
        for (int k = 0; k < 16; k++) s += wsum[k];
        blockSums[blockIdx.x] = s;
    }
}

__global__ __launch_bounds__(64) void scanB_kernel(const int* __restrict__ blockSums,
                                                   int* __restrict__ blockOffs) {
    int t = threadIdx.x;
    int v = (t < SCAN_NB) ? blockSums[t] : 0;
    int incl = v;
#pragma unroll
    for (int off = 1; off < 64; off <<= 1) {
        int u = __shfl_up(incl, off);
        if (t >= off) incl += u;
    }
    if (t < SCAN_NB) blockOffs[t] = incl - v;
}

__global__ __launch_bounds__(1024) void scanC_kernel(const int* __restrict__ deg,
                                                     const int* __restrict__ blockOffs,
                                                     int* __restrict__ cursor) {
    __shared__ int wsum[16];
    int t = threadIdx.x, lane = t & 63, w = t >> 6;
    int i = blockIdx.x * 1024 + t;
    int v = (i < N_NODES) ? deg[i] : 0;
    int incl = v;
#pragma unroll
    for (int off = 1; off < 64; off <<= 1) {
        int u = __shfl_up(incl, off);
        if (lane >= off) incl += u;
    }
    if (lane == 63) wsum[w] = incl;
    __syncthreads();
    if (t == 0) {
        int s = 0;
#pragma unroll
        for (int k = 0; k < 16; k++) { int x = wsum[k]; wsum[k] = s; s += x; }
    }
    __syncthreads();
    incl += wsum[w] + blockOffs[blockIdx.x];
    if (i < N_NODES) cursor[i] = incl - v;   // exclusive prefix
}

// ---- scatter edges into dst-sorted order, packed (src, onorm[src]) ----
// after this, cursor[i] == row_ptr[i+1]
__global__ __launch_bounds__(256) void scatter_kernel(const int* __restrict__ src,
                                                      const int* __restrict__ dst,
                                                      const float* __restrict__ onorm,
                                                      int* __restrict__ cursor,
                                                      int2* __restrict__ epack, int nE) {
    int e = blockIdx.x * 256 + threadIdx.x;
    if (e < nE) {
        int s = src[e];
        int pos = atomicAdd(&cursor[dst[e]], 1);
        int2 p; p.x = s; p.y = __float_as_int(onorm[s]);
        epack[pos] = p;
    }
}

// ---- fp32 -> bf16 bulk convert (feat -> xb) ----
__global__ __launch_bounds__(256) void cvt_kernel(const float* __restrict__ x,
                                                  unsigned short* __restrict__ xb, int n4) {
    int i = blockIdx.x * 256 + threadIdx.x;
    if (i < n4) {
        float4 v = ((const float4*)x)[i];
        ushort4 o;
        o.x = f2bf(v.x); o.y = f2bf(v.y); o.z = f2bf(v.z); o.w = f2bf(v.w);
        ((ushort4*)xb)[i] = o;
    }
}

// ---- W prep: transpose W1,W2 to n-major and split into bf16 hi + lo ----
// Wt[wi][n][k]: hi = bf16(W[k][n]), lo = bf16(W[k][n] - fp32(hi))
__global__ __launch_bounds__(128) void wprep_kernel(const float* __restrict__ W1,
                                                    const float* __restrict__ W2,
                                                    unsigned short* __restrict__ Wt_hi,
                                                    unsigned short* __restrict__ Wt_lo) {
    int bx = blockIdx.x;            // 0..255
    int wi = bx >> 7, n = bx & 127;
    const float* W = wi ? W2 : W1;
    int k = threadIdx.x;
    float v = W[k * F + n];
    unsigned short hi = f2bf(v);
    float r = v - __uint_as_float((unsigned)hi << 16);
    size_t o = (size_t)wi * F * F + (size_t)n * F + k;
    Wt_hi[o] = hi;
    Wt_lo[o] = f2bf(r);
}

// ---- atomic-free aggregation: one 64-thread wave per dst row, bf16 input ----
// OUT_BF16=1: write packed bf16 (for MFMA gemm); 0: write fp32 (layer 3)
template <int OUT_BF16>
__global__ __launch_bounds__(64) void agg_csr_kernel(const unsigned short* __restrict__ xb,
                                                     void* __restrict__ mo,
                                                     const int* __restrict__ cursor,
                                                     const int2* __restrict__ epack,
                                                     const float* __restrict__ inorm) {
    int row = blockIdx.x;
    int lane = threadIdx.x;
    int beg = (row == 0) ? 0 : cursor[row - 1];
    int end = cursor[row];
    const unsigned* xl = (const unsigned*)xb + lane;  // 2 bf16 per unsigned; row stride 64
    float ax = 0.0f, ay = 0.0f;
    int e = beg;
    for (; e + 3 < end; e += 4) {
        int2 p0 = epack[e],     p1 = epack[e + 1];
        int2 p2 = epack[e + 2], p3 = epack[e + 3];
        unsigned u0 = xl[(size_t)p0.x * 64];
        unsigned u1 = xl[(size_t)p1.x * 64];
        unsigned u2 = xl[(size_t)p2.x * 64];
        unsigned u3 = xl[(size_t)p3.x * 64];
        float w0 = __int_as_float(p0.y), w1 = __int_as_float(p1.y);
        float w2 = __int_as_float(p2.y), w3 = __int_as_float(p3.y);
        ax += bflo2f(u0) * w0 + bflo2f(u1) * w1 + bflo2f(u2) * w2 + bflo2f(u3) * w3;
        ay += bfhi2f(u0) * w0 + bfhi2f(u1) * w1 + bfhi2f(u2) * w2 + bfhi2f(u3) * w3;
    }
    for (; e < end; e++) {
        int2 p = epack[e];
        unsigned u = xl[(size_t)p.x * 64];
        float w = __int_as_float(p.y);
        ax += bflo2f(u) * w;
        ay += bfhi2f(u) * w;
    }
    float inw = inorm[row];
    ax *= inw; ay *= inw;
    if (OUT_BF16) {
        unsigned o = (unsigned)f2bf(ax) | ((unsigned)f2bf(ay) << 16);
        ((unsigned*)mo)[(size_t)row * 64 + lane] = o;
    } else {
        float2 o; o.x = ax; o.y = ay;
        ((float2*)mo)[(size_t)row * 64 + lane] = o;
    }
}

// ---- MFMA GEMM: Y = act(A @ (W_hi + W_lo) + b), A bf16 [N,128], Y bf16 ----
// block = 256 thr = 4 waves; wave handles 16 rows x 128 cols; 16x16x32 MFMA.
// A-frag: m=lane&15, k=quad*8+j.  B-frag (Wt n-major): n=lane&15, k=quad*8+j.
// D: col=lane&15, row=quad*4+reg  [verified layouts per learn_hip m89/m120]
template <int RELU>
__global__ __launch_bounds__(256) void mfma_gemm_kernel(const unsigned short* __restrict__ A,
                                                        const unsigned short* __restrict__ Wt_hi,
                                                        const unsigned short* __restrict__ Wt_lo,
                                                        const float* __restrict__ bias,
                                                        unsigned short* __restrict__ Y) {
    int w = threadIdx.x >> 6;
    int lane = threadIdx.x & 63;
    int quad = lane >> 4, r16 = lane & 15;
    int row0 = blockIdx.x * 64 + w * 16;

    f32x4 acc[8];
#pragma unroll
    for (int t = 0; t < 8; t++) acc[t] = (f32x4){0.f, 0.f, 0.f, 0.f};

    const uint4* Arow = (const uint4*)(A + (size_t)(row0 + r16) * F);
    const uint4* Bh = (const uint4*)Wt_hi;
    const uint4* Bl = (const uint4*)Wt_lo;

#pragma unroll
    for (int kk = 0; kk < 4; kk++) {
        bf16x8 a = __builtin_bit_cast(bf16x8, Arow[kk * 4 + quad]);
#pragma unroll
        for (int t = 0; t < 8; t++) {
            int boff = (t * 16 + r16) * (F / 8) + kk * 4 + quad;  // uint4 index
            bf16x8 bh = __builtin_bit_cast(bf16x8, Bh[boff]);
            bf16x8 bl = __builtin_bit_cast(bf16x8, Bl[boff]);
            acc[t] = __builtin_amdgcn_mfma_f32_16x16x32_bf16(a, bh, acc[t], 0, 0, 0);
            acc[t] = __builtin_amdgcn_mfma_f32_16x16x32_bf16(a, bl, acc[t], 0, 0, 0);
        }
    }

#pragma unroll
    for (int t = 0; t < 8; t++) {
        int col = t * 16 + r16;
        float bb = bias[col];
#pragma unroll
        for (int reg = 0; reg < 4; reg++) {
            int row = row0 + quad * 4 + reg;
            if (row < N_NODES) {
                float v = acc[t][reg] + bb;
                if (RELU) v = fmaxf(v, 0.0f);
                Y[(size_t)row * F + col] = f2bf(v);
            }
        }
    }
}

// ---- c[j] = (1/N) * sum_i m[i,j]  (fp32 m, inorm folded) ----
__global__ __launch_bounds__(128) void colmean_kernel(const float* __restrict__ m,
                                                      float* __restrict__ c, int nRows) {
    int col = threadIdx.x;
    float acc = 0.0f;
    for (int i = blockIdx.x; i < nRows; i += gridDim.x)
        acc += m[(size_t)i * F + col];
    atomicAdd(&c[col], acc * (1.0f / (float)N_NODES));
}

// ---- out[j] = b3[j] + sum_k c[k] * W3[k,j]  (fp32, exact W3) ----
__global__ __launch_bounds__(128) void out_kernel(const float* __restrict__ c,
                                                  const float* __restrict__ W,
                                                  const float* __restrict__ b,
                                                  float* __restrict__ out) {
    int j = threadIdx.x;
    float acc = b[j];
    for (int k = 0; k < F; k++) acc += c[k] * W[k * F + j];
    out[j] = acc;
}

extern "C" void kernel_launch(void* const* d_in, const int* in_sizes, int n_in,
                              void* d_out, int out_size, void* d_ws, size_t ws_size,
                              hipStream_t stream) {
    const float* feat = (const float*)d_in[0];
    const float* W1   = (const float*)d_in[1];
    const float* b1   = (const float*)d_in[2];
    const float* W2   = (const float*)d_in[3];
    const float* b2   = (const float*)d_in[4];
    const float* W3   = (const float*)d_in[5];
    const float* b3   = (const float*)d_in[6];
    const int*   src  = (const int*)d_in[7];
    const int*   dst  = (const int*)d_in[8];
    float* out = (float*)d_out;

    // workspace layout
    char* ws = (char*)d_ws;
    size_t off = 0;
    // bufA: 25.6 MB. Layers 1-2: first 12.8 MB = mb (bf16 GEMM input).
    // Layer 3: whole region = m (fp32) — mb's last use (gemm2) precedes agg3.
    float*          m     = (float*)(ws + off);
    unsigned short* mb    = (unsigned short*)(ws + off); off += (size_t)N_NODES * F * 4;
    unsigned short* hb    = (unsigned short*)(ws + off); off += (size_t)N_NODES * F * 2;
    unsigned short* xb    = (unsigned short*)(ws + off); off += (size_t)N_NODES * F * 2;
    float* onorm   = (float*)(ws + off); off += N_NODES * 4;
    float* inorm   = (float*)(ws + off); off += N_NODES * 4;
    int*   cursor  = (int*)  (ws + off); off += N_NODES * 4;
    int*   bsums   = (int*)  (ws + off); off += 64 * 4;
    int*   boffs   = (int*)  (ws + off); off += 64 * 4;
    unsigned short* Wt_hi = (unsigned short*)(ws + off); off += 2 * F * F * 2;
    unsigned short* Wt_lo = (unsigned short*)(ws + off); off += 2 * F * F * 2;
    // deg_src|deg_dst|c contiguous -> single memset
    int*   deg_src = (int*)  (ws + off); off += N_NODES * 4;
    int*   deg_dst = (int*)  (ws + off); off += N_NODES * 4;
    float* c       = (float*)(ws + off); off += F * 4;
    int2*  epack   = (int2*) (ws + off); off += (size_t)N_EDGES * 8;

    const int EB = (N_EDGES + 255) / 256;        // 3125
    const int GB = (N_NODES + 63) / 64;          // 782 (last block row-guarded)

    // zero only what accumulates: deg_src|deg_dst|c (contiguous)
    hipMemsetAsync(deg_src, 0, (2 * N_NODES + F) * sizeof(int), stream);

    // CSR build + prep
    deg_kernel<<<EB, 256, 0, stream>>>(src, dst, deg_src, deg_dst, N_EDGES);
    norm_kernel<<<(N_NODES + 255) / 256, 256, 0, stream>>>(deg_src, deg_dst, onorm, inorm, N_NODES);
    scanA_kernel<<<SCAN_NB, 1024, 0, stream>>>(deg_dst, bsums);
    scanB_kernel<<<1, 64, 0, stream>>>(bsums, boffs);
    scanC_kernel<<<SCAN_NB, 1024, 0, stream>>>(deg_dst, boffs, cursor);
    scatter_kernel<<<EB, 256, 0, stream>>>(src, dst, onorm, cursor, epack, N_EDGES);
    cvt_kernel<<<(N_NODES * F / 4 + 255) / 256, 256, 0, stream>>>(feat, xb, N_NODES * F / 4);
    wprep_kernel<<<256, 128, 0, stream>>>(W1, W2, Wt_hi, Wt_lo);

    // layer 1
    agg_csr_kernel<1><<<N_NODES, 64, 0, stream>>>(xb, mb, cursor, epack, inorm);
    mfma_gemm_kernel<1><<<GB, 256, 0, stream>>>(mb, Wt_hi, Wt_lo, b1, hb);
    // layer 2
    agg_csr_kernel<1><<<N_NODES, 64, 0, stream>>>(hb, mb, cursor, epack, inorm);
    mfma_gemm_kernel<1><<<GB, 256, 0, stream>>>(mb, Wt_hi + F * F, Wt_lo + F * F, b2, hb);
    // layer 3 + mean fusion: out = (mean_i m[i,:]) @ W3 + b3 (fp32)
    agg_csr_kernel<0><<<N_NODES, 64, 0, stream>>>(hb, m, cursor, epack, inorm);
    colmean_kernel<<<512, 128, 0, stream>>>(m, c, N_NODES);
    out_kernel<<<1, 128, 0, stream>>>(c, W3, b3, out);
}

// Round 5
// 403.426 us; speedup vs baseline: 11.0356x; 1.0249x over previous
//
#include <hip/hip_runtime.h>

// GCN: 3-layer GraphConv (norm='both') + mean over nodes.
// Round 5: zero global atomics. CSR build via chunked LDS histograms +
// column-prefix scatter (LDS cursors only). Agg at full occupancy (4-wave
// blocks) with clamped unroll-4. All activations bf16; MFMA GEMM with
// hi+lo-split weights (round 4).
#define N_NODES 50000
#define N_EDGES 800000
#define F 128
#define SCAN_NB 49      // ceil(50000/1024)
#define CH 64           // edge chunks (= hist/scatter blocks)
#define EPC (N_EDGES / CH)   // 12500 edges per chunk
#define HALF 25000      // node half-range (packed 16-bit hist)
#define QTR 12500       // node quarter-range (32-bit cursors)

typedef __bf16 bf16x8 __attribute__((ext_vector_type(8)));
typedef float  f32x4  __attribute__((ext_vector_type(4)));

__device__ inline unsigned short f2bf(float f) {  // RNE fp32 -> bf16 bits
    unsigned u = __float_as_uint(f);
    u += 0x7FFF + ((u >> 16) & 1);
    return (unsigned short)(u >> 16);
}
__device__ inline float bflo2f(unsigned u) { return __uint_as_float(u << 16); }
__device__ inline float bfhi2f(unsigned u) { return __uint_as_float(u & 0xFFFF0000u); }

// ---- chunked histograms: block c histograms its 12500 edges into LDS ----
// (16-bit packed: word j holds bins 2j / 2j+1; max count 12500 < 65536)
// writes partial hists Hs[c][0..N), Hd[c][0..N) — NO global atomics.
__global__ __launch_bounds__(1024) void hist_kernel(const int* __restrict__ src,
                                                    const int* __restrict__ dst,
                                                    int* __restrict__ Hs,
                                                    int* __restrict__ Hd) {
    __shared__ unsigned hist[HALF / 2];  // 50 KB
    int c = blockIdx.x;
    int e0 = c * EPC;
#pragma unroll
    for (int t = 0; t < 2; t++) {
        const int* ids = t ? dst : src;
        int* H = t ? Hd : Hs;
        for (int h = 0; h < 2; h++) {
            int base = h * HALF;
            for (int j = threadIdx.x; j < HALF / 2; j += 1024) hist[j] = 0;
            __syncthreads();
            for (int e = e0 + threadIdx.x; e < e0 + EPC; e += 1024) {
                int id = ids[e] - base;
                if ((unsigned)id < (unsigned)HALF)
                    atomicAdd(&hist[id >> 1], 1u << ((id & 1) * 16));
            }
            __syncthreads();
            for (int j = threadIdx.x; j < HALF / 2; j += 1024) {
                unsigned u = hist[j];
                uint2 o; o.x = u & 0xFFFFu; o.y = u >> 16;
                *(uint2*)&H[(size_t)c * N_NODES + base + 2 * j] = o;
            }
            __syncthreads();
        }
    }
}

// ---- reduce partial hists -> degrees -> norms (+ deg_dst for scan) ----
__global__ __launch_bounds__(256) void reduceN_kernel(const int* __restrict__ Hs,
                                                      const int* __restrict__ Hd,
                                                      float* __restrict__ onorm,
                                                      float* __restrict__ inorm,
                                                      int* __restrict__ degd) {
    int i = blockIdx.x * 256 + threadIdx.x;
    if (i >= N_NODES) return;
    int ds = 0, dd = 0;
    for (int c = 0; c < CH; c++) {
        ds += Hs[(size_t)c * N_NODES + i];
        dd += Hd[(size_t)c * N_NODES + i];
    }
    onorm[i] = rsqrtf(fmaxf((float)ds, 1.0f));
    inorm[i] = rsqrtf(fmaxf((float)dd, 1.0f));
    degd[i] = dd;
}

// ---- hierarchical scan: A (block sums), B (scan 49 sums), C (apply) ----
__global__ __launch_bounds__(1024) void scanA_kernel(const int* __restrict__ deg,
                                                     int* __restrict__ blockSums) {
    __shared__ int wsum[16];
    int i = blockIdx.x * 1024 + threadIdx.x;
    int v = (i < N_NODES) ? deg[i] : 0;
#pragma unroll
    for (int off = 32; off; off >>= 1) v += __shfl_down(v, off);
    if ((threadIdx.x & 63) == 0) wsum[threadIdx.x >> 6] = v;
    __syncthreads();
    if (threadIdx.x == 0) {
        int s = 0;
#pragma unroll
        for (int k = 0; k < 16; k++) s += wsum[k];
        blockSums[blockIdx.x] = s;
    }
}

__global__ __launch_bounds__(64) void scanB_kernel(const int* __restrict__ blockSums,
                                                   int* __restrict__ blockOffs) {
    int t = threadIdx.x;
    int v = (t < SCAN_NB) ? blockSums[t] : 0;
    int incl = v;
#pragma unroll
    for (int off = 1; off < 64; off <<= 1) {
        int u = __shfl_up(incl, off);
        if (t >= off) incl += u;
    }
    if (t < SCAN_NB) blockOffs[t] = incl - v;
}

// rowst[i] = exclusive prefix of deg_dst; also rowst[N] = E
__global__ __launch_bounds__(1024) void scanC_kernel(const int* __restrict__ deg,
                                                     const int* __restrict__ blockOffs,
                                                     int* __restrict__ rowst) {
    __shared__ int wsum[16];
    int t = threadIdx.x, lane = t & 63, w = t >> 6;
    int i = blockIdx.x * 1024 + t;
    int v = (i < N_NODES) ? deg[i] : 0;
    int incl = v;
#pragma unroll
    for (int off = 1; off < 64; off <<= 1) {
        int u = __shfl_up(incl, off);
        if (lane >= off) incl += u;
    }
    if (lane == 63) wsum[w] = incl;
    __syncthreads();
    if (t == 0) {
        int s = 0;
#pragma unroll
        for (int k = 0; k < 16; k++) { int x = wsum[k]; wsum[k] = s; s += x; }
    }
    __syncthreads();
    incl += wsum[w] + blockOffs[blockIdx.x];
    if (i < N_NODES) rowst[i] = incl - v;
    if (i == N_NODES - 1) rowst[N_NODES] = incl;
}

// ---- column prefix: P[c][i] = rowst[i] + sum_{c'<c} Hd[c'][i]  (in place) ----
__global__ __launch_bounds__(256) void colpref_kernel(const int* __restrict__ rowst,
                                                      int* __restrict__ Hd) {
    int i = blockIdx.x * 256 + threadIdx.x;
    if (i >= N_NODES) return;
    int s = rowst[i];
    for (int c = 0; c < CH; c++) {
        size_t o = (size_t)c * N_NODES + i;
        int t = Hd[o]; Hd[o] = s; s += t;
    }
}

// ---- atomic-free scatter: block c places its edges via LDS cursors ----
// 4 quarter-range passes; chunk slices are disjoint -> no global atomics.
__global__ __launch_bounds__(1024) void scatter2_kernel(const int* __restrict__ src,
                                                        const int* __restrict__ dst,
                                                        const float* __restrict__ onorm,
                                                        const int* __restrict__ P,
                                                        int2* __restrict__ epack) {
    __shared__ int cur[QTR];  // 50 KB
    int c = blockIdx.x;
    int e0 = c * EPC;
    for (int q = 0; q < 4; q++) {
        int base = q * QTR;
        for (int j = threadIdx.x; j < QTR; j += 1024)
            cur[j] = P[(size_t)c * N_NODES + base + j];
        __syncthreads();
        for (int e = e0 + threadIdx.x; e < e0 + EPC; e += 1024) {
            int d = dst[e] - base;
            if ((unsigned)d < (unsigned)QTR) {
                int s = src[e];
                int pos = atomicAdd(&cur[d], 1);   // LDS atomic only
                int2 p; p.x = s; p.y = __float_as_int(onorm[s]);
                epack[pos] = p;
            }
        }
        __syncthreads();
    }
}

// ---- fp32 -> bf16 bulk convert (feat -> xb) ----
__global__ __launch_bounds__(256) void cvt_kernel(const float* __restrict__ x,
                                                  unsigned short* __restrict__ xb, int n4) {
    int i = blockIdx.x * 256 + threadIdx.x;
    if (i < n4) {
        float4 v = ((const float4*)x)[i];
        ushort4 o;
        o.x = f2bf(v.x); o.y = f2bf(v.y); o.z = f2bf(v.z); o.w = f2bf(v.w);
        ((ushort4*)xb)[i] = o;
    }
}

// ---- W prep: transpose W1,W2 to n-major, split bf16 hi + lo ----
__global__ __launch_bounds__(128) void wprep_kernel(const float* __restrict__ W1,
                                                    const float* __restrict__ W2,
                                                    unsigned short* __restrict__ Wt_hi,
                                                    unsigned short* __restrict__ Wt_lo) {
    int bx = blockIdx.x;            // 0..255
    int wi = bx >> 7, n = bx & 127;
    const float* W = wi ? W2 : W1;
    int k = threadIdx.x;
    float v = W[k * F + n];
    unsigned short hi = f2bf(v);
    float r = v - __uint_as_float((unsigned)hi << 16);
    size_t o = (size_t)wi * F * F + (size_t)n * F + k;
    Wt_hi[o] = hi;
    Wt_lo[o] = f2bf(r);
}

// ---- aggregation: 4 waves/block, 1 dst row/wave, bf16 in -> bf16 out ----
// m[row,:] = inorm[row] * sum_e x[epack[e].x,:] * w(epack[e])
__global__ __launch_bounds__(256) void agg_csr_kernel(const unsigned short* __restrict__ xb,
                                                      unsigned* __restrict__ mo,
                                                      const int* __restrict__ rowst,
                                                      const int2* __restrict__ epack,
                                                      const float* __restrict__ inorm) {
    int w = threadIdx.x >> 6;
    int lane = threadIdx.x & 63;
    int row = blockIdx.x * 4 + w;
    int beg = __builtin_amdgcn_readfirstlane(rowst[row]);
    int end = __builtin_amdgcn_readfirstlane(rowst[row + 1]);
    const unsigned* xl = (const unsigned*)xb + lane;  // 2 bf16/word; row stride 64
    float ax = 0.0f, ay = 0.0f;
    for (int e = beg; e < end; e += 4) {   // clamped unroll-4, no serial tail
        int e1 = min(e + 1, end - 1), e2 = min(e + 2, end - 1), e3 = min(e + 3, end - 1);
        int2 p0 = epack[e],  p1 = epack[e1];
        int2 p2 = epack[e2], p3 = epack[e3];
        unsigned u0 = xl[(size_t)p0.x * 64];
        unsigned u1 = xl[(size_t)p1.x * 64];
        unsigned u2 = xl[(size_t)p2.x * 64];
        unsigned u3 = xl[(size_t)p3.x * 64];
        float w0 = __int_as_float(p0.y);
        float w1 = (e + 1 < end) ? __int_as_float(p1.y) : 0.0f;
        float w2 = (e + 2 < end) ? __int_as_float(p2.y) : 0.0f;
        float w3 = (e + 3 < end) ? __int_as_float(p3.y) : 0.0f;
        ax += bflo2f(u0) * w0 + bflo2f(u1) * w1 + bflo2f(u2) * w2 + bflo2f(u3) * w3;
        ay += bfhi2f(u0) * w0 + bfhi2f(u1) * w1 + bfhi2f(u2) * w2 + bfhi2f(u3) * w3;
    }
    float inw = inorm[row];
    ax *= inw; ay *= inw;
    mo[(size_t)row * 64 + lane] = (unsigned)f2bf(ax) | ((unsigned)f2bf(ay) << 16);
}

// ---- MFMA GEMM: Y = act(A @ (W_hi + W_lo) + b), A bf16 [N,128], Y bf16 ----
template <int RELU>
__global__ __launch_bounds__(256) void mfma_gemm_kernel(const unsigned short* __restrict__ A,
                                                        const unsigned short* __restrict__ Wt_hi,
                                                        const unsigned short* __restrict__ Wt_lo,
                                                        const float* __restrict__ bias,
                                                        unsigned short* __restrict__ Y) {
    int w = threadIdx.x >> 6;
    int lane = threadIdx.x & 63;
    int quad = lane >> 4, r16 = lane & 15;
    int row0 = blockIdx.x * 64 + w * 16;

    f32x4 acc[8];
#pragma unroll
    for (int t = 0; t < 8; t++) acc[t] = (f32x4){0.f, 0.f, 0.f, 0.f};

    const uint4* Arow = (const uint4*)(A + (size_t)(row0 + r16) * F);
    const uint4* Bh = (const uint4*)Wt_hi;
    const uint4* Bl = (const uint4*)Wt_lo;

#pragma unroll
    for (int kk = 0; kk < 4; kk++) {
        bf16x8 a = __builtin_bit_cast(bf16x8, Arow[kk * 4 + quad]);
#pragma unroll
        for (int t = 0; t < 8; t++) {
            int boff = (t * 16 + r16) * (F / 8) + kk * 4 + quad;  // uint4 index
            bf16x8 bh = __builtin_bit_cast(bf16x8, Bh[boff]);
            bf16x8 bl = __builtin_bit_cast(bf16x8, Bl[boff]);
            acc[t] = __builtin_amdgcn_mfma_f32_16x16x32_bf16(a, bh, acc[t], 0, 0, 0);
            acc[t] = __builtin_amdgcn_mfma_f32_16x16x32_bf16(a, bl, acc[t], 0, 0, 0);
        }
    }

#pragma unroll
    for (int t = 0; t < 8; t++) {
        int col = t * 16 + r16;
        float bb = bias[col];
#pragma unroll
        for (int reg = 0; reg < 4; reg++) {
            int row = row0 + quad * 4 + reg;
            if (row < N_NODES) {
                float v = acc[t][reg] + bb;
                if (RELU) v = fmaxf(v, 0.0f);
                Y[(size_t)row * F + col] = f2bf(v);
            }
        }
    }
}

// ---- c[j] = (1/N) * sum_i mb[i,j]  (bf16 input, fp32 accumulate) ----
__global__ __launch_bounds__(128) void colmean_kernel(const unsigned* __restrict__ mb,
                                                      float* __restrict__ c, int nRows) {
    int col = threadIdx.x;
    int word = col >> 1;
    float acc = 0.0f;
    for (int i = blockIdx.x; i < nRows; i += gridDim.x) {
        unsigned u = mb[(size_t)i * 64 + word];
        acc += (col & 1) ? bfhi2f(u) : bflo2f(u);
    }
    atomicAdd(&c[col], acc * (1.0f / (float)N_NODES));
}

// ---- out[j] = b3[j] + sum_k c[k] * W3[k,j]  (fp32, exact W3) ----
__global__ __launch_bounds__(128) void out_kernel(const float* __restrict__ c,
                                                  const float* __restrict__ W,
                                                  const float* __restrict__ b,
                                                  float* __restrict__ out) {
    int j = threadIdx.x;
    float acc = b[j];
    for (int k = 0; k < F; k++) acc += c[k] * W[k * F + j];
    out[j] = acc;
}

extern "C" void kernel_launch(void* const* d_in, const int* in_sizes, int n_in,
                              void* d_out, int out_size, void* d_ws, size_t ws_size,
                              hipStream_t stream) {
    const float* feat = (const float*)d_in[0];
    const float* W1   = (const float*)d_in[1];
    const float* b1   = (const float*)d_in[2];
    const float* W2   = (const float*)d_in[3];
    const float* b2   = (const float*)d_in[4];
    const float* W3   = (const float*)d_in[5];
    const float* b3   = (const float*)d_in[6];
    const int*   src  = (const int*)d_in[7];
    const int*   dst  = (const int*)d_in[8];
    float* out = (float*)d_out;

    // workspace layout. bufA (25.6 MB) is time-shared:
    //   CSR build:  [Hs (12.8 MB) | Hd/P (12.8 MB)]
    //   layers:     mb (bf16 agg output, 12.8 MB) aliases Hs (dead after reduceN;
    //               Hd/P dead after scatter2, before agg1 runs)
    char* ws = (char*)d_ws;
    size_t off = 0;
    int*      Hs   = (int*)(ws + off);
    unsigned* mb   = (unsigned*)(ws + off); off += (size_t)CH * N_NODES * 4;   // 12.8 MB
    int*      Hd   = (int*)(ws + off); off += (size_t)CH * N_NODES * 4;        // 12.8 MB
    unsigned short* hb = (unsigned short*)(ws + off); off += (size_t)N_NODES * F * 2;
    unsigned short* xb = (unsigned short*)(ws + off); off += (size_t)N_NODES * F * 2;
    float* onorm   = (float*)(ws + off); off += N_NODES * 4;
    float* inorm   = (float*)(ws + off); off += N_NODES * 4;
    int*   rowst   = (int*)  (ws + off); off += (N_NODES + 1) * 4;
    int*   bsums   = (int*)  (ws + off); off += 64 * 4;
    int*   boffs   = (int*)  (ws + off); off += 64 * 4;
    int*   degd    = (int*)  (ws + off); off += N_NODES * 4;
    unsigned short* Wt_hi = (unsigned short*)(ws + off); off += 2 * F * F * 2;
    unsigned short* Wt_lo = (unsigned short*)(ws + off); off += 2 * F * F * 2;
    float* c       = (float*)(ws + off); off += F * 4;
    int2*  epack   = (int2*) (ws + off); off += (size_t)N_EDGES * 8;

    const int GB = (N_NODES + 63) / 64;          // 782 (store row-guarded)

    // only c accumulates across kernels -> one tiny memset
    hipMemsetAsync(c, 0, F * sizeof(float), stream);

    // CSR build — zero global atomics
    hist_kernel<<<CH, 1024, 0, stream>>>(src, dst, Hs, Hd);
    reduceN_kernel<<<(N_NODES + 255) / 256, 256, 0, stream>>>(Hs, Hd, onorm, inorm, degd);
    scanA_kernel<<<SCAN_NB, 1024, 0, stream>>>(degd, bsums);
    scanB_kernel<<<1, 64, 0, stream>>>(bsums, boffs);
    scanC_kernel<<<SCAN_NB, 1024, 0, stream>>>(degd, boffs, rowst);
    colpref_kernel<<<(N_NODES + 255) / 256, 256, 0, stream>>>(rowst, Hd);
    scatter2_kernel<<<CH, 1024, 0, stream>>>(src, dst, onorm, Hd, epack);

    // prep
    cvt_kernel<<<(N_NODES * F / 4 + 255) / 256, 256, 0, stream>>>(feat, xb, N_NODES * F / 4);
    wprep_kernel<<<256, 128, 0, stream>>>(W1, W2, Wt_hi, Wt_lo);

    // layer 1
    agg_csr_kernel<<<N_NODES / 4, 256, 0, stream>>>(xb, mb, rowst, epack, inorm);
    mfma_gemm_kernel<1><<<GB, 256, 0, stream>>>((const unsigned short*)mb, Wt_hi, Wt_lo, b1, hb);
    // layer 2
    agg_csr_kernel<<<N_NODES / 4, 256, 0, stream>>>(hb, mb, rowst, epack, inorm);
    mfma_gemm_kernel<1><<<GB, 256, 0, stream>>>((const unsigned short*)mb, Wt_hi + F * F, Wt_lo + F * F, b2, hb);
    // layer 3 + mean fusion: out = (mean_i m[i,:]) @ W3 + b3
    agg_csr_kernel<<<N_NODES / 4, 256, 0, stream>>>(hb, mb, rowst, epack, inorm);
    colmean_kernel<<<512, 128, 0, stream>>>(mb, c, N_NODES);
    out_kernel<<<1, 128, 0, stream>>>(c, W3, b3, out);
}

// Round 6
// 355.033 us; speedup vs baseline: 12.5399x; 1.1363x over previous
//
#include <hip/hip_runtime.h>

// GCN: 3-layer GraphConv (norm='both') + mean over nodes.
// Round 6: CSR-build passes parallelized across blocks (grid 256 for hist &
// scatter), scan chain fused (reduceN+scanA, scanC+colpref), aggregation
// with 16-lane/edge uint4 gathers (4 edges per wave instruction).
#define N_NODES 50000
#define N_EDGES 800000
#define F 128
#define SCAN_NB 49      // ceil(50000/1024)
#define CH 64           // edge chunks
#define EPC (N_EDGES / CH)   // 12500 edges per chunk
#define HALF 25000      // node half-range (packed 16-bit hist)
#define QTR 12500       // node quarter-range (32-bit cursors)

typedef __bf16 bf16x8 __attribute__((ext_vector_type(8)));
typedef float  f32x4  __attribute__((ext_vector_type(4)));

__device__ inline unsigned short f2bf(float f) {  // RNE fp32 -> bf16 bits
    unsigned u = __float_as_uint(f);
    u += 0x7FFF + ((u >> 16) & 1);
    return (unsigned short)(u >> 16);
}
__device__ inline float bflo2f(unsigned u) { return __uint_as_float(u << 16); }
__device__ inline float bfhi2f(unsigned u) { return __uint_as_float(u & 0xFFFF0000u); }

// ---- chunked histograms: block = (chunk, type, half), ONE LDS pass each ----
// 256 blocks; 16-bit packed bins (chunk count <= 12500 < 65536). No global atomics.
__global__ __launch_bounds__(1024) void hist_kernel(const int* __restrict__ src,
                                                    const int* __restrict__ dst,
                                                    int* __restrict__ Hs,
                                                    int* __restrict__ Hd) {
    __shared__ unsigned hist[HALF / 2];  // 50 KB
    int bx = blockIdx.x;
    int c = bx >> 2, t = bx & 1, h = (bx >> 1) & 1;
    const int* ids = t ? dst : src;
    int* H = t ? Hd : Hs;
    int base = h * HALF;
    for (int j = threadIdx.x; j < HALF / 2; j += 1024) hist[j] = 0;
    __syncthreads();
    int e0 = c * EPC;
    for (int e = e0 + threadIdx.x; e < e0 + EPC; e += 1024) {
        int id = ids[e] - base;
        if ((unsigned)id < (unsigned)HALF)
            atomicAdd(&hist[id >> 1], 1u << ((id & 1) * 16));
    }
    __syncthreads();
    for (int j = threadIdx.x; j < HALF / 2; j += 1024) {
        unsigned u = hist[j];
        uint2 o; o.x = u & 0xFFFFu; o.y = u >> 16;
        *(uint2*)&H[(size_t)c * N_NODES + base + 2 * j] = o;
    }
}

// ---- reduce partial hists -> degrees -> norms; fused scanA block sums ----
__global__ __launch_bounds__(1024) void reduceN_kernel(const int* __restrict__ Hs,
                                                       const int* __restrict__ Hd,
                                                       float* __restrict__ onorm,
                                                       float* __restrict__ inorm,
                                                       int* __restrict__ degd,
                                                       int* __restrict__ bsums) {
    __shared__ int wsum[16];
    int i = blockIdx.x * 1024 + threadIdx.x;
    int dd = 0;
    if (i < N_NODES) {
        int ds = 0;
        for (int c = 0; c < CH; c++) {
            ds += Hs[(size_t)c * N_NODES + i];
            dd += Hd[(size_t)c * N_NODES + i];
        }
        onorm[i] = rsqrtf(fmaxf((float)ds, 1.0f));
        inorm[i] = rsqrtf(fmaxf((float)dd, 1.0f));
        degd[i] = dd;
    }
    int v = dd;
#pragma unroll
    for (int off = 32; off; off >>= 1) v += __shfl_down(v, off);
    if ((threadIdx.x & 63) == 0) wsum[threadIdx.x >> 6] = v;
    __syncthreads();
    if (threadIdx.x == 0) {
        int s = 0;
#pragma unroll
        for (int k = 0; k < 16; k++) s += wsum[k];
        bsums[blockIdx.x] = s;
    }
}

__global__ __launch_bounds__(64) void scanB_kernel(const int* __restrict__ blockSums,
                                                   int* __restrict__ blockOffs) {
    int t = threadIdx.x;
    int v = (t < SCAN_NB) ? blockSums[t] : 0;
    int incl = v;
#pragma unroll
    for (int off = 1; off < 64; off <<= 1) {
        int u = __shfl_up(incl, off);
        if (t >= off) incl += u;
    }
    if (t < SCAN_NB) blockOffs[t] = incl - v;
}

// ---- scanC + colpref fused: rowst[i] = excl prefix; then P[c][i] build ----
__global__ __launch_bounds__(1024) void scanC_kernel(const int* __restrict__ deg,
                                                     const int* __restrict__ blockOffs,
                                                     int* __restrict__ rowst,
                                                     int* __restrict__ Hd) {
    __shared__ int wsum[16];
    int t = threadIdx.x, lane = t & 63, w = t >> 6;
    int i = blockIdx.x * 1024 + t;
    int v = (i < N_NODES) ? deg[i] : 0;
    int incl = v;
#pragma unroll
    for (int off = 1; off < 64; off <<= 1) {
        int u = __shfl_up(incl, off);
        if (lane >= off) incl += u;
    }
    if (lane == 63) wsum[w] = incl;
    __syncthreads();
    if (t == 0) {
        int s = 0;
#pragma unroll
        for (int k = 0; k < 16; k++) { int x = wsum[k]; wsum[k] = s; s += x; }
    }
    __syncthreads();
    incl += wsum[w] + blockOffs[blockIdx.x];
    if (i < N_NODES) {
        int s = incl - v;          // exclusive prefix
        rowst[i] = s;
        if (i == N_NODES - 1) rowst[N_NODES] = incl;
        // colpref in place: P[c][i] = rowst[i] + sum_{c'<c} Hd[c'][i]
        for (int c = 0; c < CH; c++) {
            size_t o = (size_t)c * N_NODES + i;
            int x = Hd[o]; Hd[o] = s; s += x;
        }
    }
}

// ---- atomic-free scatter: block = (chunk, quarter), ONE pass each ----
__global__ __launch_bounds__(1024) void scatter2_kernel(const int* __restrict__ src,
                                                        const int* __restrict__ dst,
                                                        const float* __restrict__ onorm,
                                                        const int* __restrict__ P,
                                                        int2* __restrict__ epack) {
    __shared__ int cur[QTR];  // 50 KB
    int bx = blockIdx.x;
    int c = bx >> 2, q = bx & 3;
    int base = q * QTR;
    for (int j = threadIdx.x; j < QTR; j += 1024)
        cur[j] = P[(size_t)c * N_NODES + base + j];
    __syncthreads();
    int e0 = c * EPC;
    for (int e = e0 + threadIdx.x; e < e0 + EPC; e += 1024) {
        int d = dst[e] - base;
        if ((unsigned)d < (unsigned)QTR) {
            int s = src[e];
            int pos = atomicAdd(&cur[d], 1);   // LDS atomic only
            int2 p; p.x = s; p.y = __float_as_int(onorm[s]);
            epack[pos] = p;
        }
    }
}

// ---- fp32 -> bf16 bulk convert (feat -> xb) ----
__global__ __launch_bounds__(256) void cvt_kernel(const float* __restrict__ x,
                                                  unsigned short* __restrict__ xb, int n4) {
    int i = blockIdx.x * 256 + threadIdx.x;
    if (i < n4) {
        float4 v = ((const float4*)x)[i];
        ushort4 o;
        o.x = f2bf(v.x); o.y = f2bf(v.y); o.z = f2bf(v.z); o.w = f2bf(v.w);
        ((ushort4*)xb)[i] = o;
    }
}

// ---- W prep: transpose W1,W2 to n-major, split bf16 hi + lo ----
__global__ __launch_bounds__(128) void wprep_kernel(const float* __restrict__ W1,
                                                    const float* __restrict__ W2,
                                                    unsigned short* __restrict__ Wt_hi,
                                                    unsigned short* __restrict__ Wt_lo) {
    int bx = blockIdx.x;            // 0..255
    int wi = bx >> 7, n = bx & 127;
    const float* W = wi ? W2 : W1;
    int k = threadIdx.x;
    float v = W[k * F + n];
    unsigned short hi = f2bf(v);
    float r = v - __uint_as_float((unsigned)hi << 16);
    size_t o = (size_t)wi * F * F + (size_t)n * F + k;
    Wt_hi[o] = hi;
    Wt_lo[o] = f2bf(r);
}

// ---- aggregation: 4 waves/block, 1 dst row/wave; 16 lanes per edge ----
// lane = (g = lane>>4)*16 + t: group g handles edge e+g, lane covers cols
// [8t..8t+8) via one uint4 (16 B) load. Unroll-2 -> 8 edges in flight.
// Cross-group combine: shfl_xor 16/32. Lanes 0-15 write the bf16 row.
__global__ __launch_bounds__(256) void agg_csr_kernel(const unsigned short* __restrict__ xb,
                                                      unsigned* __restrict__ mo,
                                                      const int* __restrict__ rowst,
                                                      const int2* __restrict__ epack,
                                                      const float* __restrict__ inorm) {
    int w = threadIdx.x >> 6;
    int lane = threadIdx.x & 63;
    int g = lane >> 4, t = lane & 15;
    int row = blockIdx.x * 4 + w;
    int beg = __builtin_amdgcn_readfirstlane(rowst[row]);
    int end = __builtin_amdgcn_readfirstlane(rowst[row + 1]);
    const uint4* xv = (const uint4*)xb;   // row stride 16 uint4
    float acc[8];
#pragma unroll
    for (int k = 0; k < 8; k++) acc[k] = 0.0f;

    for (int e = beg; e < end; e += 8) {   // clamped, no serial tail
        int ea = min(e + g, end - 1);
        int eb = min(e + 4 + g, end - 1);
        int2 pa = epack[ea], pb = epack[eb];
        uint4 ua = xv[(size_t)pa.x * 16 + t];
        uint4 ub = xv[(size_t)pb.x * 16 + t];
        float wa = (e + g < end) ? __int_as_float(pa.y) : 0.0f;
        float wb = (e + 4 + g < end) ? __int_as_float(pb.y) : 0.0f;
        acc[0] += bflo2f(ua.x) * wa + bflo2f(ub.x) * wb;
        acc[1] += bfhi2f(ua.x) * wa + bfhi2f(ub.x) * wb;
        acc[2] += bflo2f(ua.y) * wa + bflo2f(ub.y) * wb;
        acc[3] += bfhi2f(ua.y) * wa + bfhi2f(ub.y) * wb;
        acc[4] += bflo2f(ua.z) * wa + bflo2f(ub.z) * wb;
        acc[5] += bfhi2f(ua.z) * wa + bfhi2f(ub.z) * wb;
        acc[6] += bflo2f(ua.w) * wa + bflo2f(ub.w) * wb;
        acc[7] += bfhi2f(ua.w) * wa + bfhi2f(ub.w) * wb;
    }
#pragma unroll
    for (int k = 0; k < 8; k++) {
        acc[k] += __shfl_xor(acc[k], 16, 64);
        acc[k] += __shfl_xor(acc[k], 32, 64);
    }
    if (g == 0) {
        float inw = inorm[row];
        uint4 o;
        o.x = (unsigned)f2bf(acc[0] * inw) | ((unsigned)f2bf(acc[1] * inw) << 16);
        o.y = (unsigned)f2bf(acc[2] * inw) | ((unsigned)f2bf(acc[3] * inw) << 16);
        o.z = (unsigned)f2bf(acc[4] * inw) | ((unsigned)f2bf(acc[5] * inw) << 16);
        o.w = (unsigned)f2bf(acc[6] * inw) | ((unsigned)f2bf(acc[7] * inw) << 16);
        ((uint4*)mo)[(size_t)row * 16 + t] = o;
    }
}

// ---- MFMA GEMM: Y = act(A @ (W_hi + W_lo) + b), A bf16 [N,128], Y bf16 ----
template <int RELU>
__global__ __launch_bounds__(256) void mfma_gemm_kernel(const unsigned short* __restrict__ A,
                                                        const unsigned short* __restrict__ Wt_hi,
                                                        const unsigned short* __restrict__ Wt_lo,
                                                        const float* __restrict__ bias,
                                                        unsigned short* __restrict__ Y) {
    int w = threadIdx.x >> 6;
    int lane = threadIdx.x & 63;
    int quad = lane >> 4, r16 = lane & 15;
    int row0 = blockIdx.x * 64 + w * 16;

    f32x4 acc[8];
#pragma unroll
    for (int t = 0; t < 8; t++) acc[t] = (f32x4){0.f, 0.f, 0.f, 0.f};

    const uint4* Arow = (const uint4*)(A + (size_t)(row0 + r16) * F);
    const uint4* Bh = (const uint4*)Wt_hi;
    const uint4* Bl = (const uint4*)Wt_lo;

#pragma unroll
    for (int kk = 0; kk < 4; kk++) {
        bf16x8 a = __builtin_bit_cast(bf16x8, Arow[kk * 4 + quad]);
#pragma unroll
        for (int t = 0; t < 8; t++) {
            int boff = (t * 16 + r16) * (F / 8) + kk * 4 + quad;  // uint4 index
            bf16x8 bh = __builtin_bit_cast(bf16x8, Bh[boff]);
            bf16x8 bl = __builtin_bit_cast(bf16x8, Bl[boff]);
            acc[t] = __builtin_amdgcn_mfma_f32_16x16x32_bf16(a, bh, acc[t], 0, 0, 0);
            acc[t] = __builtin_amdgcn_mfma_f32_16x16x32_bf16(a, bl, acc[t], 0, 0, 0);
        }
    }

#pragma unroll
    for (int t = 0; t < 8; t++) {
        int col = t * 16 + r16;
        float bb = bias[col];
#pragma unroll
        for (int reg = 0; reg < 4; reg++) {
            int row = row0 + quad * 4 + reg;
            if (row < N_NODES) {
                float v = acc[t][reg] + bb;
                if (RELU) v = fmaxf(v, 0.0f);
                Y[(size_t)row * F + col] = f2bf(v);
            }
        }
    }
}

// ---- c[j] = (1/N) * sum_i mb[i,j]  (bf16 input, fp32 accumulate) ----
__global__ __launch_bounds__(128) void colmean_kernel(const unsigned* __restrict__ mb,
                                                      float* __restrict__ c, int nRows) {
    int col = threadIdx.x;
    int word = col >> 1;
    float acc = 0.0f;
    for (int i = blockIdx.x; i < nRows; i += gridDim.x) {
        unsigned u = mb[(size_t)i * 64 + word];
        acc += (col & 1) ? bfhi2f(u) : bflo2f(u);
    }
    atomicAdd(&c[col], acc * (1.0f / (float)N_NODES));
}

// ---- out[j] = b3[j] + sum_k c[k] * W3[k,j]  (fp32, exact W3) ----
__global__ __launch_bounds__(128) void out_kernel(const float* __restrict__ c,
                                                  const float* __restrict__ W,
                                                  const float* __restrict__ b,
                                                  float* __restrict__ out) {
    int j = threadIdx.x;
    float acc = b[j];
    for (int k = 0; k < F; k++) acc += c[k] * W[k * F + j];
    out[j] = acc;
}

extern "C" void kernel_launch(void* const* d_in, const int* in_sizes, int n_in,
                              void* d_out, int out_size, void* d_ws, size_t ws_size,
                              hipStream_t stream) {
    const float* feat = (const float*)d_in[0];
    const float* W1   = (const float*)d_in[1];
    const float* b1   = (const float*)d_in[2];
    const float* W2   = (const float*)d_in[3];
    const float* b2   = (const float*)d_in[4];
    const float* W3   = (const float*)d_in[5];
    const float* b3   = (const float*)d_in[6];
    const int*   src  = (const int*)d_in[7];
    const int*   dst  = (const int*)d_in[8];
    float* out = (float*)d_out;

    // workspace layout. bufA (25.6 MB) time-shared:
    //   CSR build:  [Hs (12.8 MB) | Hd/P (12.8 MB)]
    //   layers:     mb aliases Hs (dead after reduceN); Hd/P dead after scatter2
    char* ws = (char*)d_ws;
    size_t off = 0;
    int*      Hs   = (int*)(ws + off);
    unsigned* mb   = (unsigned*)(ws + off); off += (size_t)CH * N_NODES * 4;   // 12.8 MB
    int*      Hd   = (int*)(ws + off); off += (size_t)CH * N_NODES * 4;        // 12.8 MB
    unsigned short* hb = (unsigned short*)(ws + off); off += (size_t)N_NODES * F * 2;
    unsigned short* xb = (unsigned short*)(ws + off); off += (size_t)N_NODES * F * 2;
    float* onorm   = (float*)(ws + off); off += N_NODES * 4;
    float* inorm   = (float*)(ws + off); off += N_NODES * 4;
    int*   rowst   = (int*)  (ws + off); off += (N_NODES + 1) * 4;
    int*   bsums   = (int*)  (ws + off); off += 64 * 4;
    int*   boffs   = (int*)  (ws + off); off += 64 * 4;
    int*   degd    = (int*)  (ws + off); off += N_NODES * 4;
    unsigned short* Wt_hi = (unsigned short*)(ws + off); off += 2 * F * F * 2;
    unsigned short* Wt_lo = (unsigned short*)(ws + off); off += 2 * F * F * 2;
    float* c       = (float*)(ws + off); off += F * 4;
    int2*  epack   = (int2*) (ws + off); off += (size_t)N_EDGES * 8;

    const int GB = (N_NODES + 63) / 64;          // 782 (store row-guarded)

    // only c accumulates across kernels -> one tiny memset
    hipMemsetAsync(c, 0, F * sizeof(float), stream);

    // CSR build — zero global atomics, all passes block-parallel
    hist_kernel<<<4 * CH, 1024, 0, stream>>>(src, dst, Hs, Hd);
    reduceN_kernel<<<SCAN_NB, 1024, 0, stream>>>(Hs, Hd, onorm, inorm, degd, bsums);
    scanB_kernel<<<1, 64, 0, stream>>>(bsums, boffs);
    scanC_kernel<<<SCAN_NB, 1024, 0, stream>>>(degd, boffs, rowst, Hd);
    scatter2_kernel<<<4 * CH, 1024, 0, stream>>>(src, dst, onorm, Hd, epack);

    // prep
    cvt_kernel<<<(N_NODES * F / 4 + 255) / 256, 256, 0, stream>>>(feat, xb, N_NODES * F / 4);
    wprep_kernel<<<256, 128, 0, stream>>>(W1, W2, Wt_hi, Wt_lo);

    // layer 1
    agg_csr_kernel<<<N_NODES / 4, 256, 0, stream>>>(xb, mb, rowst, epack, inorm);
    mfma_gemm_kernel<1><<<GB, 256, 0, stream>>>((const unsigned short*)mb, Wt_hi, Wt_lo, b1, hb);
    // layer 2
    agg_csr_kernel<<<N_NODES / 4, 256, 0, stream>>>(hb, mb, rowst, epack, inorm);
    mfma_gemm_kernel<1><<<GB, 256, 0, stream>>>((const unsigned short*)mb, Wt_hi + F * F, Wt_lo + F * F, b2, hb);
    // layer 3 + mean fusion: out = (mean_i m[i,:]) @ W3 + b3
    agg_csr_kernel<<<N_NODES / 4, 256, 0, stream>>>(hb, mb, rowst, epack, inorm);
    colmean_kernel<<<512, 128, 0, stream>>>(mb, c, N_NODES);
    out_kernel<<<1, 128, 0, stream>>>(c, W3, b3, out);
}

// Round 7
// 305.212 us; speedup vs baseline: 14.5868x; 1.1632x over previous
//
#include <hip/hip_runtime.h>

// GCN: 3-layer GraphConv (norm='both') + mean over nodes.
// Round 7: GEMM B-matrix staged through LDS (two-phase hi/lo, stride-17
// uint4 padding = optimal 8-lane/superbank for ds_read_b128); agg unroll-16
// (4 gathers in flight per 16-lane edge group).
#define N_NODES 50000
#define N_EDGES 800000
#define F 128
#define SCAN_NB 49      // ceil(50000/1024)
#define CH 64           // edge chunks
#define EPC (N_EDGES / CH)   // 12500 edges per chunk
#define HALF 25000      // node half-range (packed 16-bit hist)
#define QTR 12500       // node quarter-range (32-bit cursors)
#define BSTRIDE 17      // uint4 per B-row in LDS (odd -> conflict-free b128)

typedef __bf16 bf16x8 __attribute__((ext_vector_type(8)));
typedef float  f32x4  __attribute__((ext_vector_type(4)));

__device__ inline unsigned short f2bf(float f) {  // RNE fp32 -> bf16 bits
    unsigned u = __float_as_uint(f);
    u += 0x7FFF + ((u >> 16) & 1);
    return (unsigned short)(u >> 16);
}
__device__ inline float bflo2f(unsigned u) { return __uint_as_float(u << 16); }
__device__ inline float bfhi2f(unsigned u) { return __uint_as_float(u & 0xFFFF0000u); }

// ---- chunked histograms: block = (chunk, type, half), one LDS pass each ----
__global__ __launch_bounds__(1024) void hist_kernel(const int* __restrict__ src,
                                                    const int* __restrict__ dst,
                                                    int* __restrict__ Hs,
                                                    int* __restrict__ Hd) {
    __shared__ unsigned hist[HALF / 2];  // 50 KB
    int bx = blockIdx.x;
    int c = bx >> 2, t = bx & 1, h = (bx >> 1) & 1;
    const int* ids = t ? dst : src;
    int* H = t ? Hd : Hs;
    int base = h * HALF;
    for (int j = threadIdx.x; j < HALF / 2; j += 1024) hist[j] = 0;
    __syncthreads();
    int e0 = c * EPC;
    for (int e = e0 + threadIdx.x; e < e0 + EPC; e += 1024) {
        int id = ids[e] - base;
        if ((unsigned)id < (unsigned)HALF)
            atomicAdd(&hist[id >> 1], 1u << ((id & 1) * 16));
    }
    __syncthreads();
    for (int j = threadIdx.x; j < HALF / 2; j += 1024) {
        unsigned u = hist[j];
        uint2 o; o.x = u & 0xFFFFu; o.y = u >> 16;
        *(uint2*)&H[(size_t)c * N_NODES + base + 2 * j] = o;
    }
}

// ---- reduce partial hists -> degrees -> norms; fused scanA block sums ----
__global__ __launch_bounds__(1024) void reduceN_kernel(const int* __restrict__ Hs,
                                                       const int* __restrict__ Hd,
                                                       float* __restrict__ onorm,
                                                       float* __restrict__ inorm,
                                                       int* __restrict__ degd,
                                                       int* __restrict__ bsums) {
    __shared__ int wsum[16];
    int i = blockIdx.x * 1024 + threadIdx.x;
    int dd = 0;
    if (i < N_NODES) {
        int ds = 0;
        for (int c = 0; c < CH; c++) {
            ds += Hs[(size_t)c * N_NODES + i];
            dd += Hd[(size_t)c * N_NODES + i];
        }
        onorm[i] = rsqrtf(fmaxf((float)ds, 1.0f));
        inorm[i] = rsqrtf(fmaxf((float)dd, 1.0f));
        degd[i] = dd;
    }
    int v = dd;
#pragma unroll
    for (int off = 32; off; off >>= 1) v += __shfl_down(v, off);
    if ((threadIdx.x & 63) == 0) wsum[threadIdx.x >> 6] = v;
    __syncthreads();
    if (threadIdx.x == 0) {
        int s = 0;
#pragma unroll
        for (int k = 0; k < 16; k++) s += wsum[k];
        bsums[blockIdx.x] = s;
    }
}

__global__ __launch_bounds__(64) void scanB_kernel(const int* __restrict__ blockSums,
                                                   int* __restrict__ blockOffs) {
    int t = threadIdx.x;
    int v = (t < SCAN_NB) ? blockSums[t] : 0;
    int incl = v;
#pragma unroll
    for (int off = 1; off < 64; off <<= 1) {
        int u = __shfl_up(incl, off);
        if (t >= off) incl += u;
    }
    if (t < SCAN_NB) blockOffs[t] = incl - v;
}

// ---- scanC + colpref fused ----
__global__ __launch_bounds__(1024) void scanC_kernel(const int* __restrict__ deg,
                                                     const int* __restrict__ blockOffs,
                                                     int* __restrict__ rowst,
                                                     int* __restrict__ Hd) {
    __shared__ int wsum[16];
    int t = threadIdx.x, lane = t & 63, w = t >> 6;
    int i = blockIdx.x * 1024 + t;
    int v = (i < N_NODES) ? deg[i] : 0;
    int incl = v;
#pragma unroll
    for (int off = 1; off < 64; off <<= 1) {
        int u = __shfl_up(incl, off);
        if (lane >= off) incl += u;
    }
    if (lane == 63) wsum[w] = incl;
    __syncthreads();
    if (t == 0) {
        int s = 0;
#pragma unroll
        for (int k = 0; k < 16; k++) { int x = wsum[k]; wsum[k] = s; s += x; }
    }
    __syncthreads();
    incl += wsum[w] + blockOffs[blockIdx.x];
    if (i < N_NODES) {
        int s = incl - v;          // exclusive prefix
        rowst[i] = s;
        if (i == N_NODES - 1) rowst[N_NODES] = incl;
        for (int c = 0; c < CH; c++) {
            size_t o = (size_t)c * N_NODES + i;
            int x = Hd[o]; Hd[o] = s; s += x;
        }
    }
}

// ---- atomic-free scatter: block = (chunk, quarter) ----
__global__ __launch_bounds__(1024) void scatter2_kernel(const int* __restrict__ src,
                                                        const int* __restrict__ dst,
                                                        const float* __restrict__ onorm,
                                                        const int* __restrict__ P,
                                                        int2* __restrict__ epack) {
    __shared__ int cur[QTR];  // 50 KB
    int bx = blockIdx.x;
    int c = bx >> 2, q = bx & 3;
    int base = q * QTR;
    for (int j = threadIdx.x; j < QTR; j += 1024)
        cur[j] = P[(size_t)c * N_NODES + base + j];
    __syncthreads();
    int e0 = c * EPC;
    for (int e = e0 + threadIdx.x; e < e0 + EPC; e += 1024) {
        int d = dst[e] - base;
        if ((unsigned)d < (unsigned)QTR) {
            int s = src[e];
            int pos = atomicAdd(&cur[d], 1);   // LDS atomic only
            int2 p; p.x = s; p.y = __float_as_int(onorm[s]);
            epack[pos] = p;
        }
    }
}

// ---- fp32 -> bf16 bulk convert ----
__global__ __launch_bounds__(256) void cvt_kernel(const float* __restrict__ x,
                                                  unsigned short* __restrict__ xb, int n4) {
    int i = blockIdx.x * 256 + threadIdx.x;
    if (i < n4) {
        float4 v = ((const float4*)x)[i];
        ushort4 o;
        o.x = f2bf(v.x); o.y = f2bf(v.y); o.z = f2bf(v.z); o.w = f2bf(v.w);
        ((ushort4*)xb)[i] = o;
    }
}

// ---- W prep: transpose W1,W2 to n-major, split bf16 hi + lo ----
__global__ __launch_bounds__(128) void wprep_kernel(const float* __restrict__ W1,
                                                    const float* __restrict__ W2,
                                                    unsigned short* __restrict__ Wt_hi,
                                                    unsigned short* __restrict__ Wt_lo) {
    int bx = blockIdx.x;            // 0..255
    int wi = bx >> 7, n = bx & 127;
    const float* W = wi ? W2 : W1;
    int k = threadIdx.x;
    float v = W[k * F + n];
    unsigned short hi = f2bf(v);
    float r = v - __uint_as_float((unsigned)hi << 16);
    size_t o = (size_t)wi * F * F + (size_t)n * F + k;
    Wt_hi[o] = hi;
    Wt_lo[o] = f2bf(r);
}

// ---- aggregation: 4 waves/block, 1 dst row/wave; 16 lanes/edge, unroll-16 ----
__global__ __launch_bounds__(256) void agg_csr_kernel(const unsigned short* __restrict__ xb,
                                                      unsigned* __restrict__ mo,
                                                      const int* __restrict__ rowst,
                                                      const int2* __restrict__ epack,
                                                      const float* __restrict__ inorm) {
    int w = threadIdx.x >> 6;
    int lane = threadIdx.x & 63;
    int g = lane >> 4, t = lane & 15;
    int row = blockIdx.x * 4 + w;
    int beg = __builtin_amdgcn_readfirstlane(rowst[row]);
    int end = __builtin_amdgcn_readfirstlane(rowst[row + 1]);
    const uint4* xv = (const uint4*)xb;   // row stride 16 uint4
    float acc[8];
#pragma unroll
    for (int k = 0; k < 8; k++) acc[k] = 0.0f;

    for (int e = beg; e < end; e += 16) {   // clamped, 4 gathers in flight
        int ea = min(e + g,      end - 1);
        int eb = min(e + 4 + g,  end - 1);
        int ec = min(e + 8 + g,  end - 1);
        int ed = min(e + 12 + g, end - 1);
        int2 pa = epack[ea], pb = epack[eb], pc = epack[ec], pd = epack[ed];
        uint4 ua = xv[(size_t)pa.x * 16 + t];
        uint4 ub = xv[(size_t)pb.x * 16 + t];
        uint4 uc = xv[(size_t)pc.x * 16 + t];
        uint4 ud = xv[(size_t)pd.x * 16 + t];
        float wa = (e + g      < end) ? __int_as_float(pa.y) : 0.0f;
        float wb = (e + 4 + g  < end) ? __int_as_float(pb.y) : 0.0f;
        float wc = (e + 8 + g  < end) ? __int_as_float(pc.y) : 0.0f;
        float wd = (e + 12 + g < end) ? __int_as_float(pd.y) : 0.0f;
        acc[0] += bflo2f(ua.x) * wa + bflo2f(ub.x) * wb + bflo2f(uc.x) * wc + bflo2f(ud.x) * wd;
        acc[1] += bfhi2f(ua.x) * wa + bfhi2f(ub.x) * wb + bfhi2f(uc.x) * wc + bfhi2f(ud.x) * wd;
        acc[2] += bflo2f(ua.y) * wa + bflo2f(ub.y) * wb + bflo2f(uc.y) * wc + bflo2f(ud.y) * wd;
        acc[3] += bfhi2f(ua.y) * wa + bfhi2f(ub.y) * wb + bfhi2f(uc.y) * wc + bfhi2f(ud.y) * wd;
        acc[4] += bflo2f(ua.z) * wa + bflo2f(ub.z) * wb + bflo2f(uc.z) * wc + bflo2f(ud.z) * wd;
        acc[5] += bfhi2f(ua.z) * wa + bfhi2f(ub.z) * wb + bfhi2f(uc.z) * wc + bfhi2f(ud.z) * wd;
        acc[6] += bflo2f(ua.w) * wa + bflo2f(ub.w) * wb + bflo2f(uc.w) * wc + bflo2f(ud.w) * wd;
        acc[7] += bfhi2f(ua.w) * wa + bfhi2f(ub.w) * wb + bfhi2f(uc.w) * wc + bfhi2f(ud.w) * wd;
    }
#pragma unroll
    for (int k = 0; k < 8; k++) {
        acc[k] += __shfl_xor(acc[k], 16, 64);
        acc[k] += __shfl_xor(acc[k], 32, 64);
    }
    if (g == 0) {
        float inw = inorm[row];
        uint4 o;
        o.x = (unsigned)f2bf(acc[0] * inw) | ((unsigned)f2bf(acc[1] * inw) << 16);
        o.y = (unsigned)f2bf(acc[2] * inw) | ((unsigned)f2bf(acc[3] * inw) << 16);
        o.z = (unsigned)f2bf(acc[4] * inw) | ((unsigned)f2bf(acc[5] * inw) << 16);
        o.w = (unsigned)f2bf(acc[6] * inw) | ((unsigned)f2bf(acc[7] * inw) << 16);
        ((uint4*)mo)[(size_t)row * 16 + t] = o;
    }
}

// ---- MFMA GEMM, LDS-staged B: Y = act(A @ (W_hi + W_lo) + b) ----
// 64 rows/block (4 waves x 16). Two phases over the same 34 KB LDS buffer:
// stage Wt_hi -> MFMA pass -> restage Wt_lo -> MFMA pass. A-frags preloaded
// to registers so the global A-loads overlap the first staging.
// B LDS layout: row n at uint4 offset n*BSTRIDE (17, odd -> ds_read_b128
// spreads 8 lanes/superbank = conflict-free minimum).
template <int RELU>
__global__ __launch_bounds__(256) void mfma_gemm_kernel(const unsigned short* __restrict__ A,
                                                        const unsigned short* __restrict__ Wt_hi,
                                                        const unsigned short* __restrict__ Wt_lo,
                                                        const float* __restrict__ bias,
                                                        unsigned short* __restrict__ Y) {
    __shared__ uint4 sB[F * BSTRIDE];   // 34816 B
    int tid = threadIdx.x;
    int w = tid >> 6;
    int lane = tid & 63;
    int quad = lane >> 4, r16 = lane & 15;
    int row0 = blockIdx.x * 64 + w * 16;

    // preload A-frags (global) before staging so loads overlap LDS writes
    const uint4* Arow = (const uint4*)(A + (size_t)(row0 + r16) * F);
    uint4 a[4];
#pragma unroll
    for (int kk = 0; kk < 4; kk++) a[kk] = Arow[kk * 4 + quad];

    f32x4 acc[8];
#pragma unroll
    for (int t = 0; t < 8; t++) acc[t] = (f32x4){0.f, 0.f, 0.f, 0.f};

    const uint4* G[2] = {(const uint4*)Wt_hi, (const uint4*)Wt_lo};
#pragma unroll
    for (int ph = 0; ph < 2; ph++) {
        if (ph) __syncthreads();           // all reads of hi done before restage
        for (int j = tid; j < F * 16; j += 256)
            sB[(j >> 4) * BSTRIDE + (j & 15)] = G[ph][j];
        __syncthreads();
#pragma unroll
        for (int kk = 0; kk < 4; kk++) {
            bf16x8 av = __builtin_bit_cast(bf16x8, a[kk]);
#pragma unroll
            for (int t = 0; t < 8; t++) {
                bf16x8 bv = __builtin_bit_cast(bf16x8,
                    sB[(t * 16 + r16) * BSTRIDE + kk * 4 + quad]);
                acc[t] = __builtin_amdgcn_mfma_f32_16x16x32_bf16(av, bv, acc[t], 0, 0, 0);
            }
        }
    }

#pragma unroll
    for (int t = 0; t < 8; t++) {
        int col = t * 16 + r16;
        float bb = bias[col];
#pragma unroll
        for (int reg = 0; reg < 4; reg++) {
            int row = row0 + quad * 4 + reg;
            if (row < N_NODES) {
                float v = acc[t][reg] + bb;
                if (RELU) v = fmaxf(v, 0.0f);
                Y[(size_t)row * F + col] = f2bf(v);
            }
        }
    }
}

// ---- c[j] = (1/N) * sum_i mb[i,j]  (bf16 input, fp32 accumulate) ----
__global__ __launch_bounds__(128) void colmean_kernel(const unsigned* __restrict__ mb,
                                                      float* __restrict__ c, int nRows) {
    int col = threadIdx.x;
    int word = col >> 1;
    float acc = 0.0f;
    for (int i = blockIdx.x; i < nRows; i += gridDim.x) {
        unsigned u = mb[(size_t)i * 64 + word];
        acc += (col & 1) ? bfhi2f(u) : bflo2f(u);
    }
    atomicAdd(&c[col], acc * (1.0f / (float)N_NODES));
}

// ---- out[j] = b3[j] + sum_k c[k] * W3[k,j]  (fp32, exact W3) ----
__global__ __launch_bounds__(128) void out_kernel(const float* __restrict__ c,
                                                  const float* __restrict__ W,
                                                  const float* __restrict__ b,
                                                  float* __restrict__ out) {
    int j = threadIdx.x;
    float acc = b[j];
    for (int k = 0; k < F; k++) acc += c[k] * W[k * F + j];
    out[j] = acc;
}

extern "C" void kernel_launch(void* const* d_in, const int* in_sizes, int n_in,
                              void* d_out, int out_size, void* d_ws, size_t ws_size,
                              hipStream_t stream) {
    const float* feat = (const float*)d_in[0];
    const float* W1   = (const float*)d_in[1];
    const float* b1   = (const float*)d_in[2];
    const float* W2   = (const float*)d_in[3];
    const float* b2   = (const float*)d_in[4];
    const float* W3   = (const float*)d_in[5];
    const float* b3   = (const float*)d_in[6];
    const int*   src  = (const int*)d_in[7];
    const int*   dst  = (const int*)d_in[8];
    float* out = (float*)d_out;

    // workspace layout. bufA (25.6 MB) time-shared:
    //   CSR build:  [Hs (12.8 MB) | Hd/P (12.8 MB)]
    //   layers:     mb aliases Hs (dead after reduceN); Hd/P dead after scatter2
    char* ws = (char*)d_ws;
    size_t off = 0;
    int*      Hs   = (int*)(ws + off);
    unsigned* mb   = (unsigned*)(ws + off); off += (size_t)CH * N_NODES * 4;   // 12.8 MB
    int*      Hd   = (int*)(ws + off); off += (size_t)CH * N_NODES * 4;        // 12.8 MB
    unsigned short* hb = (unsigned short*)(ws + off); off += (size_t)N_NODES * F * 2;
    unsigned short* xb = (unsigned short*)(ws + off); off += (size_t)N_NODES * F * 2;
    float* onorm   = (float*)(ws + off); off += N_NODES * 4;
    float* inorm   = (float*)(ws + off); off += N_NODES * 4;
    int*   rowst   = (int*)  (ws + off); off += (N_NODES + 1) * 4;
    int*   bsums   = (int*)  (ws + off); off += 64 * 4;
    int*   boffs   = (int*)  (ws + off); off += 64 * 4;
    int*   degd    = (int*)  (ws + off); off += N_NODES * 4;
    unsigned short* Wt_hi = (unsigned short*)(ws + off); off += 2 * F * F * 2;
    unsigned short* Wt_lo = (unsigned short*)(ws + off); off += 2 * F * F * 2;
    float* c       = (float*)(ws + off); off += F * 4;
    int2*  epack   = (int2*) (ws + off); off += (size_t)N_EDGES * 8;

    const int GB = (N_NODES + 63) / 64;          // 782 (store row-guarded)

    // only c accumulates across kernels -> one tiny memset
    hipMemsetAsync(c, 0, F * sizeof(float), stream);

    // CSR build — zero global atomics, all passes block-parallel
    hist_kernel<<<4 * CH, 1024, 0, stream>>>(src, dst, Hs, Hd);
    reduceN_kernel<<<SCAN_NB, 1024, 0, stream>>>(Hs, Hd, onorm, inorm, degd, bsums);
    scanB_kernel<<<1, 64, 0, stream>>>(bsums, boffs);
    scanC_kernel<<<SCAN_NB, 1024, 0, stream>>>(degd, boffs, rowst, Hd);
    scatter2_kernel<<<4 * CH, 1024, 0, stream>>>(src, dst, onorm, Hd, epack);

    // prep
    cvt_kernel<<<(N_NODES * F / 4 + 255) / 256, 256, 0, stream>>>(feat, xb, N_NODES * F / 4);
    wprep_kernel<<<256, 128, 0, stream>>>(W1, W2, Wt_hi, Wt_lo);

    // layer 1
    agg_csr_kernel<<<N_NODES / 4, 256, 0, stream>>>(xb, mb, rowst, epack, inorm);
    mfma_gemm_kernel<1><<<GB, 256, 0, stream>>>((const unsigned short*)mb, Wt_hi, Wt_lo, b1, hb);
    // layer 2
    agg_csr_kernel<<<N_NODES / 4, 256, 0, stream>>>(hb, mb, rowst, epack, inorm);
    mfma_gemm_kernel<1><<<GB, 256, 0, stream>>>((const unsigned short*)mb, Wt_hi + F * F, Wt_lo + F * F, b2, hb);
    // layer 3 + mean fusion: out = (mean_i m[i,:]) @ W3 + b3
    agg_csr_kernel<<<N_NODES / 4, 256, 0, stream>>>(hb, mb, rowst, epack, inorm);
    colmean_kernel<<<512, 128, 0, stream>>>(mb, c, N_NODES);
    out_kernel<<<1, 128, 0, stream>>>(c, W3, b3, out);
}